// Round 1
// baseline (1060.084 us; speedup 1.0000x reference)
//
#include <hip/hip_runtime.h>

// HierarchicalGraphSAGE: 3x SAGEConv(add-aggr) + mean-pool + linear, fp32.
// N=50000, E=800000, D=128, OUT=64, G=64.
//
// Pipeline per call (all on `stream`, graph-capture safe):
//  1. Build CSR by dst: histogram -> single-block scan -> fill (atomic slot).
//  2. Per layer: k_aggregate (wave per node, CSR sum) -> k_sage (fp32 SGEMM
//     h_out = relu?(agg@Wl^T + bl + h@Wr^T), 64-node x 128-j block tile).
//  3. k_pool (sorted-batch run-length partial sums, few atomics) -> k_final.

#define THREADS_HIST 256

__global__ void k_hist(const int* __restrict__ dst, int* __restrict__ counts, int E) {
    int e = blockIdx.x * blockDim.x + threadIdx.x;
    if (e < E) atomicAdd(&counts[dst[e]], 1);
}

// Single-block exclusive scan over n counts -> starts[0..n] (starts[n]=total).
__global__ void k_scan(const int* __restrict__ counts, int* __restrict__ starts, int n) {
    __shared__ int tot[1024];
    int t = threadIdx.x;
    int per = (n + 1023) / 1024;
    int s0 = t * per;
    int e0 = min(s0 + per, n);
    int sum = 0;
    for (int i = s0; i < e0; ++i) sum += counts[i];
    tot[t] = sum;
    __syncthreads();
    for (int off = 1; off < 1024; off <<= 1) {
        int v = (t >= off) ? tot[t - off] : 0;
        __syncthreads();
        tot[t] += v;
        __syncthreads();
    }
    int run = (t == 0) ? 0 : tot[t - 1];
    for (int i = s0; i < e0; ++i) { starts[i] = run; run += counts[i]; }
    if (t == 1023) starts[n] = tot[1023];
}

__global__ void k_copy(const int* __restrict__ src, int* __restrict__ dstv, int n) {
    int i = blockIdx.x * blockDim.x + threadIdx.x;
    if (i < n) dstv[i] = src[i];
}

__global__ void k_fill(const int* __restrict__ ei, int* __restrict__ pos,
                       int* __restrict__ csr_src, int E) {
    int e = blockIdx.x * blockDim.x + threadIdx.x;
    if (e >= E) return;
    int s = ei[e];
    int d = ei[E + e];
    int p = atomicAdd(&pos[d], 1);
    csr_src[p] = s;
}

// One wave (64 lanes) per node: agg[node] = sum over in-edges of h[src].
__global__ __launch_bounds__(256) void k_aggregate(
    const float* __restrict__ h, const int* __restrict__ starts,
    const int* __restrict__ csr_src, float* __restrict__ agg, int n)
{
    int node = blockIdx.x * 4 + (threadIdx.x >> 6);
    int lane = threadIdx.x & 63;
    if (node >= n) return;
    int s = starts[node], e = starts[node + 1];
    float2 acc = make_float2(0.f, 0.f);
    for (int i = s; i < e; ++i) {
        int src = csr_src[i];
        float2 v = *(const float2*)(h + (size_t)src * 128 + lane * 2);
        acc.x += v.x;
        acc.y += v.y;
    }
    *(float2*)(agg + (size_t)node * 128 + lane * 2) = acc;
}

// h_out[node][j] = relu?( bl[j] + agg[node]·Wl[j] + h[node]·Wr[j] )
// Block: 64 nodes x 128 j, 128 threads; thread tile 8 nodes x 8 j.
// A tile (agg|h concat, 64x256 f32 = 64KB LDS) row-rotated by nd+(nd>>3)
// float4-slots so the 4 concurrent node-rows per wave hit distinct banks.
__global__ __launch_bounds__(128) void k_sage(
    const float* __restrict__ agg, const float* __restrict__ h,
    const float* __restrict__ Wl, const float* __restrict__ bl,
    const float* __restrict__ Wr, float* __restrict__ out, int n, int do_relu)
{
    __shared__ float sA[64 * 256];  // 64 KiB
    int node0 = blockIdx.x * 64;
    int t = threadIdx.x;

    // Stage 64 nodes x (128 agg + 128 h) as float4, swizzled.
    for (int q = t; q < 4096; q += 128) {
        int nd = q >> 6;
        int c4 = q & 63;  // logical float4 col: 0..31 agg, 32..63 h
        int node = node0 + nd;
        float4 v = make_float4(0.f, 0.f, 0.f, 0.f);
        if (node < n) {
            if (c4 < 32) v = *(const float4*)(agg + (size_t)node * 128 + c4 * 4);
            else         v = *(const float4*)(h + (size_t)node * 128 + (c4 - 32) * 4);
        }
        int dst4 = (c4 + nd + (nd >> 3)) & 63;
        *(float4*)(&sA[nd * 256 + dst4 * 4]) = v;
    }
    __syncthreads();

    int jg = t & 15;   // 16 groups x 8 j
    int ng = t >> 4;   // 8 groups x 8 nodes
    int j0 = jg * 8;

    float acc[8][8];
#pragma unroll
    for (int i = 0; i < 8; ++i)
#pragma unroll
        for (int jj = 0; jj < 8; ++jj) acc[i][jj] = bl[j0 + jj];

    for (int k = 0; k < 128; k += 4) {
        int k4 = k >> 2;
        // agg · Wl
        {
            float4 w[8];
#pragma unroll
            for (int jj = 0; jj < 8; ++jj)
                w[jj] = *(const float4*)(Wl + (size_t)(j0 + jj) * 128 + k);
#pragma unroll
            for (int i = 0; i < 8; ++i) {
                int nd = ng * 8 + i;
                int rot = nd + (nd >> 3);
                float4 a = *(const float4*)(&sA[nd * 256 + ((k4 + rot) & 63) * 4]);
#pragma unroll
                for (int jj = 0; jj < 8; ++jj) {
                    acc[i][jj] += a.x * w[jj].x + a.y * w[jj].y
                                + a.z * w[jj].z + a.w * w[jj].w;
                }
            }
        }
        // h · Wr
        {
            float4 w[8];
#pragma unroll
            for (int jj = 0; jj < 8; ++jj)
                w[jj] = *(const float4*)(Wr + (size_t)(j0 + jj) * 128 + k);
#pragma unroll
            for (int i = 0; i < 8; ++i) {
                int nd = ng * 8 + i;
                int rot = nd + (nd >> 3);
                float4 hh = *(const float4*)(&sA[nd * 256 + ((k4 + 32 + rot) & 63) * 4]);
#pragma unroll
                for (int jj = 0; jj < 8; ++jj) {
                    acc[i][jj] += hh.x * w[jj].x + hh.y * w[jj].y
                                + hh.z * w[jj].z + hh.w * w[jj].w;
                }
            }
        }
    }

#pragma unroll
    for (int i = 0; i < 8; ++i) {
        int node = node0 + ng * 8 + i;
        if (node >= n) continue;
#pragma unroll
        for (int jb = 0; jb < 2; ++jb) {
            float4 v = make_float4(acc[i][jb * 4 + 0], acc[i][jb * 4 + 1],
                                   acc[i][jb * 4 + 2], acc[i][jb * 4 + 3]);
            if (do_relu) {
                v.x = fmaxf(v.x, 0.f); v.y = fmaxf(v.y, 0.f);
                v.z = fmaxf(v.z, 0.f); v.w = fmaxf(v.w, 0.f);
            }
            *(float4*)(out + (size_t)node * 128 + j0 + jb * 4) = v;
        }
    }
}

// batch is sorted: run-length accumulate per block chunk, flush on change.
__global__ __launch_bounds__(128) void k_pool(
    const float* __restrict__ h, const int* __restrict__ batch,
    float* __restrict__ gsum, float* __restrict__ gcnt, int n)
{
    int f = threadIdx.x;  // 0..127
    int start = blockIdx.x * 256;
    if (start >= n) return;
    int end = min(start + 256, n);
    int cur = batch[start];
    float acc = 0.f, cnt = 0.f;
    for (int i = start; i < end; ++i) {
        int g = batch[i];
        if (g != cur) {
            atomicAdd(&gsum[cur * 128 + f], acc);
            if (f == 0) atomicAdd(&gcnt[cur], cnt);
            acc = 0.f; cnt = 0.f; cur = g;
        }
        acc += h[(size_t)i * 128 + f];
        cnt += 1.f;
    }
    atomicAdd(&gsum[cur * 128 + f], acc);
    if (f == 0) atomicAdd(&gcnt[cur], cnt);
}

__global__ void k_final(const float* __restrict__ gsum, const float* __restrict__ gcnt,
                        const float* __restrict__ Wlin, const float* __restrict__ blin,
                        float* __restrict__ out)
{
    int g = blockIdx.x;   // 64
    int o = threadIdx.x;  // 64
    float inv = 1.f / fmaxf(gcnt[g], 1.f);
    float acc = 0.f;
    for (int k = 0; k < 128; ++k)
        acc += gsum[g * 128 + k] * Wlin[o * 128 + k];
    out[g * 64 + o] = acc * inv + blin[o];
}

extern "C" void kernel_launch(void* const* d_in, const int* in_sizes, int n_in,
                              void* d_out, int out_size, void* d_ws, size_t ws_size,
                              hipStream_t stream) {
    const float* x    = (const float*)d_in[0];
    const int*   ei   = (const int*)d_in[1];
    const int*   batch = (const int*)d_in[2];
    const float* W1l = (const float*)d_in[3];
    const float* b1l = (const float*)d_in[4];
    const float* W1r = (const float*)d_in[5];
    const float* W2l = (const float*)d_in[6];
    const float* b2l = (const float*)d_in[7];
    const float* W2r = (const float*)d_in[8];
    const float* W3l = (const float*)d_in[9];
    const float* b3l = (const float*)d_in[10];
    const float* W3r = (const float*)d_in[11];
    const float* Wlin = (const float*)d_in[12];
    const float* blin = (const float*)d_in[13];

    const int N = in_sizes[2];       // 50000
    const int E = in_sizes[1] / 2;   // 800000

    // Workspace carve-up (256B aligned)
    size_t off = 0;
    auto alloc = [&](size_t bytes) {
        void* p = (char*)d_ws + off;
        off += (bytes + 255) & ~(size_t)255;
        return p;
    };
    int*   csr_start = (int*)alloc((size_t)(N + 1) * 4);
    int*   pos       = (int*)alloc((size_t)N * 4);
    int*   csr_src   = (int*)alloc((size_t)E * 4);
    float* aggb      = (float*)alloc((size_t)N * 128 * 4);
    float* h1        = (float*)alloc((size_t)N * 128 * 4);
    float* h2        = (float*)alloc((size_t)N * 128 * 4);
    float* gsum      = (float*)alloc((size_t)64 * 128 * 4);
    float* gcnt      = (float*)alloc((size_t)64 * 4);
    (void)ws_size;

    // --- CSR build ---
    hipMemsetAsync(pos, 0, (size_t)N * 4, stream);
    hipMemsetAsync(gsum, 0, (size_t)64 * 128 * 4, stream);
    hipMemsetAsync(gcnt, 0, (size_t)64 * 4, stream);

    k_hist<<<(E + 255) / 256, 256, 0, stream>>>(ei + E, pos, E);
    k_scan<<<1, 1024, 0, stream>>>(pos, csr_start, N);
    k_copy<<<(N + 255) / 256, 256, 0, stream>>>(csr_start, pos, N);
    k_fill<<<(E + 255) / 256, 256, 0, stream>>>(ei, pos, csr_src, E);

    int agg_grid  = (N + 3) / 4;
    int sage_grid = (N + 63) / 64;

    // Layer 1: x -> h1 (relu)
    k_aggregate<<<agg_grid, 256, 0, stream>>>(x, csr_start, csr_src, aggb, N);
    k_sage<<<sage_grid, 128, 0, stream>>>(aggb, x, W1l, b1l, W1r, h1, N, 1);
    // Layer 2: h1 -> h2 (relu)
    k_aggregate<<<agg_grid, 256, 0, stream>>>(h1, csr_start, csr_src, aggb, N);
    k_sage<<<sage_grid, 128, 0, stream>>>(aggb, h1, W2l, b2l, W2r, h2, N, 1);
    // Layer 3: h2 -> h1 (no relu)
    k_aggregate<<<agg_grid, 256, 0, stream>>>(h2, csr_start, csr_src, aggb, N);
    k_sage<<<sage_grid, 128, 0, stream>>>(aggb, h2, W3l, b3l, W3r, h1, N, 0);

    // Pool + head
    k_pool<<<(N + 255) / 256, 128, 0, stream>>>(h1, batch, gsum, gcnt, N);
    k_final<<<64, 64, 0, stream>>>(gsum, gcnt, Wlin, blin, (float*)d_out);
}

// Round 2
// 772.813 us; speedup vs baseline: 1.3717x; 1.3717x over previous
//
#include <hip/hip_runtime.h>

// HierarchicalGraphSAGE fp32 -> bf16-MFMA version.
// N=50000, E=800000, D=128, OUT=64, G=64.
//
//  1. CSR build by dst (histogram -> scan -> fill).
//  2. Cast x and weights to bf16; weights split hi/lo (compensated) so weight
//     precision stays ~fp32: acc = mfma(a,Whi,acc); acc = mfma(a,Wlo,acc).
//  3. Per layer: k_agg (wave/node, bf16 gather, fp32 accum) ->
//     k_sage (MFMA 16x16x32 bf16, M-tile 64 x N 128, K=256 = [agg|h]@[Wl|Wr]^T).
//  4. k_pool (sorted batch run-length) -> k_final.

typedef __bf16 bf16x8 __attribute__((ext_vector_type(8)));
typedef float f32x4 __attribute__((ext_vector_type(4)));

static __device__ __forceinline__ float bf2f(unsigned short u) {
    union { unsigned u; float f; } c; c.u = (unsigned)u << 16; return c.f;
}
static __device__ __forceinline__ unsigned short f2bf(float f) {
    unsigned u = __builtin_bit_cast(unsigned, f);
    return (unsigned short)((u + 0x7fffu + ((u >> 16) & 1u)) >> 16);
}

// ---------------- CSR build ----------------
__global__ void k_hist(const int* __restrict__ dst, int* __restrict__ counts, int E) {
    int e = blockIdx.x * blockDim.x + threadIdx.x;
    if (e < E) atomicAdd(&counts[dst[e]], 1);
}

__global__ void k_scan(const int* __restrict__ counts, int* __restrict__ starts, int n) {
    __shared__ int tot[1024];
    int t = threadIdx.x;
    int per = (n + 1023) / 1024;
    int s0 = t * per;
    int e0 = min(s0 + per, n);
    int sum = 0;
    for (int i = s0; i < e0; ++i) sum += counts[i];
    tot[t] = sum;
    __syncthreads();
    for (int off = 1; off < 1024; off <<= 1) {
        int v = (t >= off) ? tot[t - off] : 0;
        __syncthreads();
        tot[t] += v;
        __syncthreads();
    }
    int run = (t == 0) ? 0 : tot[t - 1];
    for (int i = s0; i < e0; ++i) { starts[i] = run; run += counts[i]; }
    if (t == 1023) starts[n] = tot[1023];
}

__global__ void k_copy(const int* __restrict__ src, int* __restrict__ dstv, int n) {
    int i = blockIdx.x * blockDim.x + threadIdx.x;
    if (i < n) dstv[i] = src[i];
}

__global__ void k_fill(const int* __restrict__ ei, int* __restrict__ pos,
                       int* __restrict__ csr_src, int E) {
    int e = blockIdx.x * blockDim.x + threadIdx.x;
    if (e >= E) return;
    int s = ei[e];
    int d = ei[E + e];
    int p = atomicAdd(&pos[d], 1);
    csr_src[p] = s;
}

// ---------------- casts ----------------
__global__ void k_cast_x(const float* __restrict__ x, unsigned short* __restrict__ xb, int n4) {
    int i = blockIdx.x * blockDim.x + threadIdx.x;  // one float4 per thread
    if (i >= n4) return;
    float4 v = *(const float4*)(x + (size_t)i * 4);
    ushort4 o;
    o.x = f2bf(v.x); o.y = f2bf(v.y); o.z = f2bf(v.z); o.w = f2bf(v.w);
    *(ushort4*)(xb + (size_t)i * 4) = o;
}

// Build Wcat = [Wl | Wr] rows [128 x 256], split into bf16 hi + lo.
__global__ void k_cast_w(const float* __restrict__ Wl, const float* __restrict__ Wr,
                         unsigned short* __restrict__ Whi, unsigned short* __restrict__ Wlo) {
    int row = blockIdx.x;    // 128
    int col = threadIdx.x;   // 256
    float w = (col < 128) ? Wl[row * 128 + col] : Wr[row * 128 + col - 128];
    unsigned short hi = f2bf(w);
    float lo = w - bf2f(hi);
    Whi[row * 256 + col] = hi;
    Wlo[row * 256 + col] = f2bf(lo);
}

// ---------------- aggregate: one wave per node, bf16 gather ----------------
__global__ __launch_bounds__(256) void k_agg(
    const unsigned short* __restrict__ hb, const int* __restrict__ starts,
    const int* __restrict__ csr, unsigned short* __restrict__ aggb, int n)
{
    int node = blockIdx.x * 4 + (threadIdx.x >> 6);
    int lane = threadIdx.x & 63;
    if (node >= n) return;
    int s = starts[node], e = starts[node + 1];
    float ax = 0.f, ay = 0.f;
    for (int i = s; i < e; ++i) {
        int src = csr[i];
        unsigned v = *(const unsigned*)(hb + (size_t)src * 128 + lane * 2);
        ax += bf2f((unsigned short)(v & 0xffffu));
        ay += bf2f((unsigned short)(v >> 16));
    }
    unsigned o = (unsigned)f2bf(ax) | ((unsigned)f2bf(ay) << 16);
    *(unsigned*)(aggb + (size_t)node * 128 + lane * 2) = o;
}

// ---------------- SAGE layer GEMM via bf16 MFMA ----------------
// C[m][j] = relu?( bl[j] + sum_k A[m][k]*W[j][k] ), A=[agg|h] (K=256),
// W=[Wl|Wr] hi+lo split. Block: 256 thr = 4 waves, tile 64 m x 128 j.
// LDS: A tile 64 rows x 264 ushort (pad -> 2-way bank alias only).
__global__ __launch_bounds__(256) void k_sage(
    const unsigned short* __restrict__ aggb, const unsigned short* __restrict__ hb,
    const unsigned short* __restrict__ Whi, const unsigned short* __restrict__ Wlo,
    const float* __restrict__ bl, unsigned short* __restrict__ outb, int n, int do_relu)
{
    __shared__ unsigned short sA[64 * 264];  // 33792 B
    int node0 = blockIdx.x * 64;
    int t = threadIdx.x;

    // Stage A tile: 64 rows x 32 chunks of 8 bf16 (agg cols 0-15, h cols 16-31).
    for (int q = t; q < 2048; q += 256) {
        int nd = q >> 5;
        int c = q & 31;
        int node = node0 + nd;
        uint4 v = make_uint4(0u, 0u, 0u, 0u);
        if (node < n) {
            const unsigned short* src = (c < 16)
                ? (aggb + (size_t)node * 128 + c * 8)
                : (hb + (size_t)node * 128 + (c - 16) * 8);
            v = *(const uint4*)src;
        }
        *(uint4*)(sA + nd * 264 + c * 8) = v;
    }
    __syncthreads();

    int wv = t >> 6;
    int l = t & 63;
    int quad = l >> 4;
    int mr = l & 15;

    f32x4 acc[8];
#pragma unroll
    for (int jt = 0; jt < 8; ++jt) acc[jt] = (f32x4){0.f, 0.f, 0.f, 0.f};

    const unsigned short* arow = sA + (wv * 16 + mr) * 264;
    for (int s = 0; s < 8; ++s) {
        int koff = s * 32 + quad * 8;
        bf16x8 a = __builtin_bit_cast(bf16x8, *(const uint4*)(arow + koff));
#pragma unroll
        for (int jt = 0; jt < 8; ++jt) {
            size_t wo = (size_t)(jt * 16 + mr) * 256 + koff;
            bf16x8 bh = __builtin_bit_cast(bf16x8, *(const uint4*)(Whi + wo));
            bf16x8 bo = __builtin_bit_cast(bf16x8, *(const uint4*)(Wlo + wo));
            acc[jt] = __builtin_amdgcn_mfma_f32_16x16x32_bf16(a, bh, acc[jt], 0, 0, 0);
            acc[jt] = __builtin_amdgcn_mfma_f32_16x16x32_bf16(a, bo, acc[jt], 0, 0, 0);
        }
    }

    // Epilogue: C/D layout col=lane&15, row=quad*4+reg.
#pragma unroll
    for (int jt = 0; jt < 8; ++jt) {
        int col = jt * 16 + mr;
        float bias = bl[col];
#pragma unroll
        for (int r = 0; r < 4; ++r) {
            int node = node0 + wv * 16 + quad * 4 + r;
            if (node >= n) continue;
            float v = acc[jt][r] + bias;
            if (do_relu) v = fmaxf(v, 0.f);
            outb[(size_t)node * 128 + col] = f2bf(v);
        }
    }
}

// ---------------- pool + head ----------------
__global__ __launch_bounds__(128) void k_pool(
    const unsigned short* __restrict__ hb, const int* __restrict__ batch,
    float* __restrict__ gsum, float* __restrict__ gcnt, int n)
{
    int f = threadIdx.x;  // 0..127
    int start = blockIdx.x * 256;
    if (start >= n) return;
    int end = min(start + 256, n);
    int cur = batch[start];
    float acc = 0.f, cnt = 0.f;
    for (int i = start; i < end; ++i) {
        int g = batch[i];
        if (g != cur) {
            atomicAdd(&gsum[cur * 128 + f], acc);
            if (f == 0) atomicAdd(&gcnt[cur], cnt);
            acc = 0.f; cnt = 0.f; cur = g;
        }
        acc += bf2f(hb[(size_t)i * 128 + f]);
        cnt += 1.f;
    }
    atomicAdd(&gsum[cur * 128 + f], acc);
    if (f == 0) atomicAdd(&gcnt[cur], cnt);
}

__global__ void k_final(const float* __restrict__ gsum, const float* __restrict__ gcnt,
                        const float* __restrict__ Wlin, const float* __restrict__ blin,
                        float* __restrict__ out)
{
    int g = blockIdx.x;   // 64
    int o = threadIdx.x;  // 64
    float inv = 1.f / fmaxf(gcnt[g], 1.f);
    float acc = 0.f;
    for (int k = 0; k < 128; ++k)
        acc += gsum[g * 128 + k] * Wlin[o * 128 + k];
    out[g * 64 + o] = acc * inv + blin[o];
}

extern "C" void kernel_launch(void* const* d_in, const int* in_sizes, int n_in,
                              void* d_out, int out_size, void* d_ws, size_t ws_size,
                              hipStream_t stream) {
    const float* x     = (const float*)d_in[0];
    const int*   ei    = (const int*)d_in[1];
    const int*   batch = (const int*)d_in[2];
    const float* W1l = (const float*)d_in[3];
    const float* b1l = (const float*)d_in[4];
    const float* W1r = (const float*)d_in[5];
    const float* W2l = (const float*)d_in[6];
    const float* b2l = (const float*)d_in[7];
    const float* W2r = (const float*)d_in[8];
    const float* W3l = (const float*)d_in[9];
    const float* b3l = (const float*)d_in[10];
    const float* W3r = (const float*)d_in[11];
    const float* Wlin = (const float*)d_in[12];
    const float* blin = (const float*)d_in[13];

    const int N = in_sizes[2];       // 50000
    const int E = in_sizes[1] / 2;   // 800000

    size_t off = 0;
    auto alloc = [&](size_t bytes) {
        void* p = (char*)d_ws + off;
        off += (bytes + 255) & ~(size_t)255;
        return p;
    };
    int* csr_start = (int*)alloc((size_t)(N + 1) * 4);
    int* pos       = (int*)alloc((size_t)N * 4);
    int* csr_src   = (int*)alloc((size_t)E * 4);
    unsigned short* x_bf   = (unsigned short*)alloc((size_t)N * 128 * 2);
    unsigned short* hA     = (unsigned short*)alloc((size_t)N * 128 * 2);
    unsigned short* hB     = (unsigned short*)alloc((size_t)N * 128 * 2);
    unsigned short* agg_bf = (unsigned short*)alloc((size_t)N * 128 * 2);
    unsigned short* W1hi = (unsigned short*)alloc(128 * 256 * 2);
    unsigned short* W1lo = (unsigned short*)alloc(128 * 256 * 2);
    unsigned short* W2hi = (unsigned short*)alloc(128 * 256 * 2);
    unsigned short* W2lo = (unsigned short*)alloc(128 * 256 * 2);
    unsigned short* W3hi = (unsigned short*)alloc(128 * 256 * 2);
    unsigned short* W3lo = (unsigned short*)alloc(128 * 256 * 2);
    float* gsum = (float*)alloc((size_t)64 * 128 * 4);
    float* gcnt = (float*)alloc((size_t)64 * 4);
    (void)ws_size;

    hipMemsetAsync(pos, 0, (size_t)N * 4, stream);
    hipMemsetAsync(gsum, 0, (size_t)64 * 128 * 4, stream);
    hipMemsetAsync(gcnt, 0, (size_t)64 * 4, stream);

    // CSR build
    k_hist<<<(E + 255) / 256, 256, 0, stream>>>(ei + E, pos, E);
    k_scan<<<1, 1024, 0, stream>>>(pos, csr_start, N);
    k_copy<<<(N + 255) / 256, 256, 0, stream>>>(csr_start, pos, N);
    k_fill<<<(E + 255) / 256, 256, 0, stream>>>(ei, pos, csr_src, E);

    // Casts
    int n4 = N * 128 / 4;
    k_cast_x<<<(n4 + 255) / 256, 256, 0, stream>>>(x, x_bf, n4);
    k_cast_w<<<128, 256, 0, stream>>>(W1l, W1r, W1hi, W1lo);
    k_cast_w<<<128, 256, 0, stream>>>(W2l, W2r, W2hi, W2lo);
    k_cast_w<<<128, 256, 0, stream>>>(W3l, W3r, W3hi, W3lo);

    int agg_grid = (N + 3) / 4;
    int sage_grid = (N + 63) / 64;

    // Layer 1: x_bf -> hA (relu)
    k_agg<<<agg_grid, 256, 0, stream>>>(x_bf, csr_start, csr_src, agg_bf, N);
    k_sage<<<sage_grid, 256, 0, stream>>>(agg_bf, x_bf, W1hi, W1lo, b1l, hA, N, 1);
    // Layer 2: hA -> hB (relu)
    k_agg<<<agg_grid, 256, 0, stream>>>(hA, csr_start, csr_src, agg_bf, N);
    k_sage<<<sage_grid, 256, 0, stream>>>(agg_bf, hA, W2hi, W2lo, b2l, hB, N, 1);
    // Layer 3: hB -> hA (no relu)
    k_agg<<<agg_grid, 256, 0, stream>>>(hB, csr_start, csr_src, agg_bf, N);
    k_sage<<<sage_grid, 256, 0, stream>>>(agg_bf, hB, W3hi, W3lo, b3l, hA, N, 0);

    // Pool + head
    k_pool<<<(N + 255) / 256, 128, 0, stream>>>(hA, batch, gsum, gcnt, N);
    k_final<<<64, 64, 0, stream>>>(gsum, gcnt, Wlin, blin, (float*)d_out);
}

// Round 3
// 503.580 us; speedup vs baseline: 2.1051x; 1.5346x over previous
//
#include <hip/hip_runtime.h>

// HierarchicalGraphSAGE bf16-MFMA version, R3.
// N=50000, E=800000, D=128, OUT=64, G=64.
//
//  R3 changes vs R2:
//   - k_agg: 64-wide index batch via one vector load + __shfl broadcast,
//     edge loop 4-deep load pipelining (was 1 load in flight -> latency-bound,
//     VALUBusy 16.5%).
//   - k_sage: wave owns a 32-col j-strip instead of duplicating all 128 cols
//     -> per-wave global weight traffic drops 128KB -> 16KB (B fragments held
//     in VGPRs across the 4 m-subtiles).

typedef __bf16 bf16x8 __attribute__((ext_vector_type(8)));
typedef float f32x4 __attribute__((ext_vector_type(4)));

static __device__ __forceinline__ float bf2f(unsigned short u) {
    union { unsigned u; float f; } c; c.u = (unsigned)u << 16; return c.f;
}
static __device__ __forceinline__ unsigned short f2bf(float f) {
    unsigned u = __builtin_bit_cast(unsigned, f);
    return (unsigned short)((u + 0x7fffu + ((u >> 16) & 1u)) >> 16);
}

// ---------------- CSR build ----------------
__global__ void k_hist(const int* __restrict__ dst, int* __restrict__ counts, int E) {
    int e = blockIdx.x * blockDim.x + threadIdx.x;
    if (e < E) atomicAdd(&counts[dst[e]], 1);
}

__global__ void k_scan(const int* __restrict__ counts, int* __restrict__ starts, int n) {
    __shared__ int tot[1024];
    int t = threadIdx.x;
    int per = (n + 1023) / 1024;
    int s0 = t * per;
    int e0 = min(s0 + per, n);
    int sum = 0;
    for (int i = s0; i < e0; ++i) sum += counts[i];
    tot[t] = sum;
    __syncthreads();
    for (int off = 1; off < 1024; off <<= 1) {
        int v = (t >= off) ? tot[t - off] : 0;
        __syncthreads();
        tot[t] += v;
        __syncthreads();
    }
    int run = (t == 0) ? 0 : tot[t - 1];
    for (int i = s0; i < e0; ++i) { starts[i] = run; run += counts[i]; }
    if (t == 1023) starts[n] = tot[1023];
}

__global__ void k_copy(const int* __restrict__ src, int* __restrict__ dstv, int n) {
    int i = blockIdx.x * blockDim.x + threadIdx.x;
    if (i < n) dstv[i] = src[i];
}

__global__ void k_fill(const int* __restrict__ ei, int* __restrict__ pos,
                       int* __restrict__ csr_src, int E) {
    int e = blockIdx.x * blockDim.x + threadIdx.x;
    if (e >= E) return;
    int s = ei[e];
    int d = ei[E + e];
    int p = atomicAdd(&pos[d], 1);
    csr_src[p] = s;
}

// ---------------- casts ----------------
__global__ void k_cast_x(const float* __restrict__ x, unsigned short* __restrict__ xb, int n4) {
    int i = blockIdx.x * blockDim.x + threadIdx.x;
    if (i >= n4) return;
    float4 v = *(const float4*)(x + (size_t)i * 4);
    ushort4 o;
    o.x = f2bf(v.x); o.y = f2bf(v.y); o.z = f2bf(v.z); o.w = f2bf(v.w);
    *(ushort4*)(xb + (size_t)i * 4) = o;
}

// Wcat = [Wl | Wr] rows [128 x 256], split into bf16 hi + lo.
__global__ void k_cast_w(const float* __restrict__ Wl, const float* __restrict__ Wr,
                         unsigned short* __restrict__ Whi, unsigned short* __restrict__ Wlo) {
    int row = blockIdx.x;    // 128
    int col = threadIdx.x;   // 256
    float w = (col < 128) ? Wl[row * 128 + col] : Wr[row * 128 + col - 128];
    unsigned short hi = f2bf(w);
    float lo = w - bf2f(hi);
    Whi[row * 256 + col] = hi;
    Wlo[row * 256 + col] = f2bf(lo);
}

// ---------------- aggregate: wave/node, batched indices, 4-deep loads ------
__global__ __launch_bounds__(256) void k_agg(
    const unsigned short* __restrict__ hb, const int* __restrict__ starts,
    const int* __restrict__ csr, unsigned short* __restrict__ aggb, int n)
{
    int node = blockIdx.x * 4 + (threadIdx.x >> 6);
    int lane = threadIdx.x & 63;
    if (node >= n) return;
    int s = starts[node], e = starts[node + 1];
    const unsigned short* hlane = hb + lane * 2;
    float ax = 0.f, ay = 0.f;
    for (int base = s; base < e; base += 64) {
        int cnt = min(64, e - base);
        int idx = (base + lane < e) ? csr[base + lane] : 0;
        int j = 0;
        for (; j + 4 <= cnt; j += 4) {
            int s0 = __shfl(idx, j + 0);
            int s1 = __shfl(idx, j + 1);
            int s2 = __shfl(idx, j + 2);
            int s3 = __shfl(idx, j + 3);
            unsigned v0 = *(const unsigned*)(hlane + (size_t)s0 * 128);
            unsigned v1 = *(const unsigned*)(hlane + (size_t)s1 * 128);
            unsigned v2 = *(const unsigned*)(hlane + (size_t)s2 * 128);
            unsigned v3 = *(const unsigned*)(hlane + (size_t)s3 * 128);
            ax += __builtin_bit_cast(float, v0 << 16);
            ay += __builtin_bit_cast(float, v0 & 0xffff0000u);
            ax += __builtin_bit_cast(float, v1 << 16);
            ay += __builtin_bit_cast(float, v1 & 0xffff0000u);
            ax += __builtin_bit_cast(float, v2 << 16);
            ay += __builtin_bit_cast(float, v2 & 0xffff0000u);
            ax += __builtin_bit_cast(float, v3 << 16);
            ay += __builtin_bit_cast(float, v3 & 0xffff0000u);
        }
        for (; j < cnt; ++j) {
            int s0 = __shfl(idx, j);
            unsigned v0 = *(const unsigned*)(hlane + (size_t)s0 * 128);
            ax += __builtin_bit_cast(float, v0 << 16);
            ay += __builtin_bit_cast(float, v0 & 0xffff0000u);
        }
    }
    unsigned o = (unsigned)f2bf(ax) | ((unsigned)f2bf(ay) << 16);
    *(unsigned*)(aggb + (size_t)node * 128 + lane * 2) = o;
}

// ---------------- SAGE layer GEMM via bf16 MFMA ----------------
// C[m][j] = relu?( bl[j] + sum_k A[m][k]*W[j][k] ), A=[agg|h] (K=256).
// Block 256 thr = 4 waves, tile 64 m x 128 j. Wave w owns j-strip
// [32w, 32w+32): B frags (hi/lo x 2 jj) stay in VGPRs across 4 m-subtiles.
__global__ __launch_bounds__(256) void k_sage(
    const unsigned short* __restrict__ aggb, const unsigned short* __restrict__ hb,
    const unsigned short* __restrict__ Whi, const unsigned short* __restrict__ Wlo,
    const float* __restrict__ bl, unsigned short* __restrict__ outb, int n, int do_relu)
{
    __shared__ unsigned short sA[64 * 264];  // 33792 B
    int node0 = blockIdx.x * 64;
    int t = threadIdx.x;

    // Stage A tile: 64 rows x 32 chunks of 8 bf16 (agg cols 0-15, h cols 16-31).
    for (int q = t; q < 2048; q += 256) {
        int nd = q >> 5;
        int c = q & 31;
        int node = node0 + nd;
        uint4 v = make_uint4(0u, 0u, 0u, 0u);
        if (node < n) {
            const unsigned short* src = (c < 16)
                ? (aggb + (size_t)node * 128 + c * 8)
                : (hb + (size_t)node * 128 + (c - 16) * 8);
            v = *(const uint4*)src;
        }
        *(uint4*)(sA + nd * 264 + c * 8) = v;
    }
    __syncthreads();

    int wv = t >> 6;     // wave -> j strip [wv*32, wv*32+32)
    int l = t & 63;
    int quad = l >> 4;
    int mr = l & 15;
    int jbase = wv * 32;

    f32x4 acc[4][2];
#pragma unroll
    for (int mi = 0; mi < 4; ++mi)
#pragma unroll
        for (int jj = 0; jj < 2; ++jj) acc[mi][jj] = (f32x4){0.f, 0.f, 0.f, 0.f};

    for (int s = 0; s < 8; ++s) {
        int koff = s * 32 + quad * 8;
        bf16x8 bh[2], bo[2];
#pragma unroll
        for (int jj = 0; jj < 2; ++jj) {
            size_t wo = (size_t)(jbase + jj * 16 + mr) * 256 + koff;
            bh[jj] = __builtin_bit_cast(bf16x8, *(const uint4*)(Whi + wo));
            bo[jj] = __builtin_bit_cast(bf16x8, *(const uint4*)(Wlo + wo));
        }
#pragma unroll
        for (int mi = 0; mi < 4; ++mi) {
            bf16x8 a = __builtin_bit_cast(
                bf16x8, *(const uint4*)(sA + (mi * 16 + mr) * 264 + koff));
#pragma unroll
            for (int jj = 0; jj < 2; ++jj) {
                acc[mi][jj] = __builtin_amdgcn_mfma_f32_16x16x32_bf16(a, bh[jj], acc[mi][jj], 0, 0, 0);
                acc[mi][jj] = __builtin_amdgcn_mfma_f32_16x16x32_bf16(a, bo[jj], acc[mi][jj], 0, 0, 0);
            }
        }
    }

    // Epilogue: C/D layout col=lane&15, row=quad*4+reg.
#pragma unroll
    for (int mi = 0; mi < 4; ++mi) {
#pragma unroll
        for (int jj = 0; jj < 2; ++jj) {
            int col = jbase + jj * 16 + mr;
            float bias = bl[col];
#pragma unroll
            for (int r = 0; r < 4; ++r) {
                int node = node0 + mi * 16 + quad * 4 + r;
                if (node >= n) continue;
                float v = acc[mi][jj][r] + bias;
                if (do_relu) v = fmaxf(v, 0.f);
                outb[(size_t)node * 128 + col] = f2bf(v);
            }
        }
    }
}

// ---------------- pool + head ----------------
__global__ __launch_bounds__(128) void k_pool(
    const unsigned short* __restrict__ hb, const int* __restrict__ batch,
    float* __restrict__ gsum, float* __restrict__ gcnt, int n)
{
    int f = threadIdx.x;  // 0..127
    int start = blockIdx.x * 256;
    if (start >= n) return;
    int end = min(start + 256, n);
    int cur = batch[start];
    float acc = 0.f, cnt = 0.f;
    for (int i = start; i < end; ++i) {
        int g = batch[i];
        if (g != cur) {
            atomicAdd(&gsum[cur * 128 + f], acc);
            if (f == 0) atomicAdd(&gcnt[cur], cnt);
            acc = 0.f; cnt = 0.f; cur = g;
        }
        acc += bf2f(hb[(size_t)i * 128 + f]);
        cnt += 1.f;
    }
    atomicAdd(&gsum[cur * 128 + f], acc);
    if (f == 0) atomicAdd(&gcnt[cur], cnt);
}

__global__ void k_final(const float* __restrict__ gsum, const float* __restrict__ gcnt,
                        const float* __restrict__ Wlin, const float* __restrict__ blin,
                        float* __restrict__ out)
{
    int g = blockIdx.x;   // 64
    int o = threadIdx.x;  // 64
    float inv = 1.f / fmaxf(gcnt[g], 1.f);
    float acc = 0.f;
    for (int k = 0; k < 128; ++k)
        acc += gsum[g * 128 + k] * Wlin[o * 128 + k];
    out[g * 64 + o] = acc * inv + blin[o];
}

extern "C" void kernel_launch(void* const* d_in, const int* in_sizes, int n_in,
                              void* d_out, int out_size, void* d_ws, size_t ws_size,
                              hipStream_t stream) {
    const float* x     = (const float*)d_in[0];
    const int*   ei    = (const int*)d_in[1];
    const int*   batch = (const int*)d_in[2];
    const float* W1l = (const float*)d_in[3];
    const float* b1l = (const float*)d_in[4];
    const float* W1r = (const float*)d_in[5];
    const float* W2l = (const float*)d_in[6];
    const float* b2l = (const float*)d_in[7];
    const float* W2r = (const float*)d_in[8];
    const float* W3l = (const float*)d_in[9];
    const float* b3l = (const float*)d_in[10];
    const float* W3r = (const float*)d_in[11];
    const float* Wlin = (const float*)d_in[12];
    const float* blin = (const float*)d_in[13];

    const int N = in_sizes[2];       // 50000
    const int E = in_sizes[1] / 2;   // 800000

    size_t off = 0;
    auto alloc = [&](size_t bytes) {
        void* p = (char*)d_ws + off;
        off += (bytes + 255) & ~(size_t)255;
        return p;
    };
    int* csr_start = (int*)alloc((size_t)(N + 1) * 4);
    int* pos       = (int*)alloc((size_t)N * 4);
    int* csr_src   = (int*)alloc((size_t)E * 4);
    unsigned short* x_bf   = (unsigned short*)alloc((size_t)N * 128 * 2);
    unsigned short* hA     = (unsigned short*)alloc((size_t)N * 128 * 2);
    unsigned short* hB     = (unsigned short*)alloc((size_t)N * 128 * 2);
    unsigned short* agg_bf = (unsigned short*)alloc((size_t)N * 128 * 2);
    unsigned short* W1hi = (unsigned short*)alloc(128 * 256 * 2);
    unsigned short* W1lo = (unsigned short*)alloc(128 * 256 * 2);
    unsigned short* W2hi = (unsigned short*)alloc(128 * 256 * 2);
    unsigned short* W2lo = (unsigned short*)alloc(128 * 256 * 2);
    unsigned short* W3hi = (unsigned short*)alloc(128 * 256 * 2);
    unsigned short* W3lo = (unsigned short*)alloc(128 * 256 * 2);
    float* gsum = (float*)alloc((size_t)64 * 128 * 4);
    float* gcnt = (float*)alloc((size_t)64 * 4);
    (void)ws_size;

    hipMemsetAsync(pos, 0, (size_t)N * 4, stream);
    hipMemsetAsync(gsum, 0, (size_t)64 * 128 * 4, stream);
    hipMemsetAsync(gcnt, 0, (size_t)64 * 4, stream);

    // CSR build
    k_hist<<<(E + 255) / 256, 256, 0, stream>>>(ei + E, pos, E);
    k_scan<<<1, 1024, 0, stream>>>(pos, csr_start, N);
    k_copy<<<(N + 255) / 256, 256, 0, stream>>>(csr_start, pos, N);
    k_fill<<<(E + 255) / 256, 256, 0, stream>>>(ei, pos, csr_src, E);

    // Casts
    int n4 = N * 128 / 4;
    k_cast_x<<<(n4 + 255) / 256, 256, 0, stream>>>(x, x_bf, n4);
    k_cast_w<<<128, 256, 0, stream>>>(W1l, W1r, W1hi, W1lo);
    k_cast_w<<<128, 256, 0, stream>>>(W2l, W2r, W2hi, W2lo);
    k_cast_w<<<128, 256, 0, stream>>>(W3l, W3r, W3hi, W3lo);

    int agg_grid = (N + 3) / 4;
    int sage_grid = (N + 63) / 64;

    // Layer 1: x_bf -> hA (relu)
    k_agg<<<agg_grid, 256, 0, stream>>>(x_bf, csr_start, csr_src, agg_bf, N);
    k_sage<<<sage_grid, 256, 0, stream>>>(agg_bf, x_bf, W1hi, W1lo, b1l, hA, N, 1);
    // Layer 2: hA -> hB (relu)
    k_agg<<<agg_grid, 256, 0, stream>>>(hA, csr_start, csr_src, agg_bf, N);
    k_sage<<<sage_grid, 256, 0, stream>>>(agg_bf, hA, W2hi, W2lo, b2l, hB, N, 1);
    // Layer 3: hB -> hA (no relu)
    k_agg<<<agg_grid, 256, 0, stream>>>(hB, csr_start, csr_src, agg_bf, N);
    k_sage<<<sage_grid, 256, 0, stream>>>(agg_bf, hB, W3hi, W3lo, b3l, hA, N, 0);

    // Pool + head
    k_pool<<<(N + 255) / 256, 128, 0, stream>>>(hA, batch, gsum, gcnt, N);
    k_final<<<64, 64, 0, stream>>>(gsum, gcnt, Wlin, blin, (float*)d_out);
}

// Round 4
// 431.203 us; speedup vs baseline: 2.4584x; 1.1678x over previous
//
#include <hip/hip_runtime.h>

// HierarchicalGraphSAGE bf16-MFMA version, R4.
// N=50000, E=800000, D=128, OUT=64, G=64.
//
//  R4 change vs R3: single-block k_scan (77us, 0.15% occupancy, top dispatch)
//  replaced by 3-level hierarchical scan (k_scan1/2/3, full-grid) with the
//  pos-copy folded into pass 3. Everything else unchanged.

typedef __bf16 bf16x8 __attribute__((ext_vector_type(8)));
typedef float f32x4 __attribute__((ext_vector_type(4)));

static __device__ __forceinline__ float bf2f(unsigned short u) {
    union { unsigned u; float f; } c; c.u = (unsigned)u << 16; return c.f;
}
static __device__ __forceinline__ unsigned short f2bf(float f) {
    unsigned u = __builtin_bit_cast(unsigned, f);
    return (unsigned short)((u + 0x7fffu + ((u >> 16) & 1u)) >> 16);
}

// ---------------- CSR build ----------------
__global__ void k_hist(const int* __restrict__ dst, int* __restrict__ counts, int E) {
    int e = blockIdx.x * blockDim.x + threadIdx.x;
    if (e < E) atomicAdd(&counts[dst[e]], 1);
}

// Pass 1: per-block (256 counts) sum.
__global__ __launch_bounds__(256) void k_scan1(
    const int* __restrict__ counts, int* __restrict__ bsum, int n)
{
    __shared__ int s[4];
    int i = blockIdx.x * 256 + threadIdx.x;
    int v = (i < n) ? counts[i] : 0;
#pragma unroll
    for (int off = 1; off < 64; off <<= 1) v += __shfl_xor(v, off);
    if ((threadIdx.x & 63) == 0) s[threadIdx.x >> 6] = v;
    __syncthreads();
    if (threadIdx.x == 0) bsum[blockIdx.x] = s[0] + s[1] + s[2] + s[3];
}

// Pass 2: single block scans nb (<=256) block sums; exclusive offsets + total.
__global__ __launch_bounds__(256) void k_scan2(
    const int* __restrict__ bsum, int* __restrict__ boff, int nb, int* __restrict__ total_out)
{
    __shared__ int s[256];
    int t = threadIdx.x;
    int v = (t < nb) ? bsum[t] : 0;
    s[t] = v;
    __syncthreads();
#pragma unroll
    for (int off = 1; off < 256; off <<= 1) {
        int u = (t >= off) ? s[t - off] : 0;
        __syncthreads();
        s[t] += u;
        __syncthreads();
    }
    if (t < nb) boff[t] = s[t] - v;
    if (t == nb - 1) *total_out = s[t];
}

// Pass 3: local exclusive scan + block offset -> starts[i]; also pos[i]=starts[i].
__global__ __launch_bounds__(256) void k_scan3(
    const int* __restrict__ counts, const int* __restrict__ boff,
    int* __restrict__ starts, int* __restrict__ pos, int n)
{
    __shared__ int s[256];
    int t = threadIdx.x;
    int i = blockIdx.x * 256 + t;
    int v = (i < n) ? counts[i] : 0;
    s[t] = v;
    __syncthreads();
#pragma unroll
    for (int off = 1; off < 256; off <<= 1) {
        int u = (t >= off) ? s[t - off] : 0;
        __syncthreads();
        s[t] += u;
        __syncthreads();
    }
    if (i < n) {
        int st = boff[blockIdx.x] + s[t] - v;
        starts[i] = st;
        pos[i] = st;
    }
}

__global__ void k_fill(const int* __restrict__ ei, int* __restrict__ pos,
                       int* __restrict__ csr_src, int E) {
    int e = blockIdx.x * blockDim.x + threadIdx.x;
    if (e >= E) return;
    int s = ei[e];
    int d = ei[E + e];
    int p = atomicAdd(&pos[d], 1);
    csr_src[p] = s;
}

// ---------------- casts ----------------
__global__ void k_cast_x(const float* __restrict__ x, unsigned short* __restrict__ xb, int n4) {
    int i = blockIdx.x * blockDim.x + threadIdx.x;
    if (i >= n4) return;
    float4 v = *(const float4*)(x + (size_t)i * 4);
    ushort4 o;
    o.x = f2bf(v.x); o.y = f2bf(v.y); o.z = f2bf(v.z); o.w = f2bf(v.w);
    *(ushort4*)(xb + (size_t)i * 4) = o;
}

// Wcat = [Wl | Wr] rows [128 x 256], split into bf16 hi + lo.
__global__ void k_cast_w(const float* __restrict__ Wl, const float* __restrict__ Wr,
                         unsigned short* __restrict__ Whi, unsigned short* __restrict__ Wlo) {
    int row = blockIdx.x;    // 128
    int col = threadIdx.x;   // 256
    float w = (col < 128) ? Wl[row * 128 + col] : Wr[row * 128 + col - 128];
    unsigned short hi = f2bf(w);
    float lo = w - bf2f(hi);
    Whi[row * 256 + col] = hi;
    Wlo[row * 256 + col] = f2bf(lo);
}

// ---------------- aggregate: wave/node, batched indices, 4-deep loads ------
__global__ __launch_bounds__(256) void k_agg(
    const unsigned short* __restrict__ hb, const int* __restrict__ starts,
    const int* __restrict__ csr, unsigned short* __restrict__ aggb, int n)
{
    int node = blockIdx.x * 4 + (threadIdx.x >> 6);
    int lane = threadIdx.x & 63;
    if (node >= n) return;
    int s = starts[node], e = starts[node + 1];
    const unsigned short* hlane = hb + lane * 2;
    float ax = 0.f, ay = 0.f;
    for (int base = s; base < e; base += 64) {
        int cnt = min(64, e - base);
        int idx = (base + lane < e) ? csr[base + lane] : 0;
        int j = 0;
        for (; j + 4 <= cnt; j += 4) {
            int s0 = __shfl(idx, j + 0);
            int s1 = __shfl(idx, j + 1);
            int s2 = __shfl(idx, j + 2);
            int s3 = __shfl(idx, j + 3);
            unsigned v0 = *(const unsigned*)(hlane + (size_t)s0 * 128);
            unsigned v1 = *(const unsigned*)(hlane + (size_t)s1 * 128);
            unsigned v2 = *(const unsigned*)(hlane + (size_t)s2 * 128);
            unsigned v3 = *(const unsigned*)(hlane + (size_t)s3 * 128);
            ax += __builtin_bit_cast(float, v0 << 16);
            ay += __builtin_bit_cast(float, v0 & 0xffff0000u);
            ax += __builtin_bit_cast(float, v1 << 16);
            ay += __builtin_bit_cast(float, v1 & 0xffff0000u);
            ax += __builtin_bit_cast(float, v2 << 16);
            ay += __builtin_bit_cast(float, v2 & 0xffff0000u);
            ax += __builtin_bit_cast(float, v3 << 16);
            ay += __builtin_bit_cast(float, v3 & 0xffff0000u);
        }
        for (; j < cnt; ++j) {
            int s0 = __shfl(idx, j);
            unsigned v0 = *(const unsigned*)(hlane + (size_t)s0 * 128);
            ax += __builtin_bit_cast(float, v0 << 16);
            ay += __builtin_bit_cast(float, v0 & 0xffff0000u);
        }
    }
    unsigned o = (unsigned)f2bf(ax) | ((unsigned)f2bf(ay) << 16);
    *(unsigned*)(aggb + (size_t)node * 128 + lane * 2) = o;
}

// ---------------- SAGE layer GEMM via bf16 MFMA ----------------
// C[m][j] = relu?( bl[j] + sum_k A[m][k]*W[j][k] ), A=[agg|h] (K=256).
// Block 256 thr = 4 waves, tile 64 m x 128 j. Wave w owns j-strip
// [32w, 32w+32): B frags (hi/lo x 2 jj) stay in VGPRs across 4 m-subtiles.
__global__ __launch_bounds__(256) void k_sage(
    const unsigned short* __restrict__ aggb, const unsigned short* __restrict__ hb,
    const unsigned short* __restrict__ Whi, const unsigned short* __restrict__ Wlo,
    const float* __restrict__ bl, unsigned short* __restrict__ outb, int n, int do_relu)
{
    __shared__ unsigned short sA[64 * 264];  // 33792 B
    int node0 = blockIdx.x * 64;
    int t = threadIdx.x;

    for (int q = t; q < 2048; q += 256) {
        int nd = q >> 5;
        int c = q & 31;
        int node = node0 + nd;
        uint4 v = make_uint4(0u, 0u, 0u, 0u);
        if (node < n) {
            const unsigned short* src = (c < 16)
                ? (aggb + (size_t)node * 128 + c * 8)
                : (hb + (size_t)node * 128 + (c - 16) * 8);
            v = *(const uint4*)src;
        }
        *(uint4*)(sA + nd * 264 + c * 8) = v;
    }
    __syncthreads();

    int wv = t >> 6;
    int l = t & 63;
    int quad = l >> 4;
    int mr = l & 15;
    int jbase = wv * 32;

    f32x4 acc[4][2];
#pragma unroll
    for (int mi = 0; mi < 4; ++mi)
#pragma unroll
        for (int jj = 0; jj < 2; ++jj) acc[mi][jj] = (f32x4){0.f, 0.f, 0.f, 0.f};

    for (int s = 0; s < 8; ++s) {
        int koff = s * 32 + quad * 8;
        bf16x8 bh[2], bo[2];
#pragma unroll
        for (int jj = 0; jj < 2; ++jj) {
            size_t wo = (size_t)(jbase + jj * 16 + mr) * 256 + koff;
            bh[jj] = __builtin_bit_cast(bf16x8, *(const uint4*)(Whi + wo));
            bo[jj] = __builtin_bit_cast(bf16x8, *(const uint4*)(Wlo + wo));
        }
#pragma unroll
        for (int mi = 0; mi < 4; ++mi) {
            bf16x8 a = __builtin_bit_cast(
                bf16x8, *(const uint4*)(sA + (mi * 16 + mr) * 264 + koff));
#pragma unroll
            for (int jj = 0; jj < 2; ++jj) {
                acc[mi][jj] = __builtin_amdgcn_mfma_f32_16x16x32_bf16(a, bh[jj], acc[mi][jj], 0, 0, 0);
                acc[mi][jj] = __builtin_amdgcn_mfma_f32_16x16x32_bf16(a, bo[jj], acc[mi][jj], 0, 0, 0);
            }
        }
    }

#pragma unroll
    for (int mi = 0; mi < 4; ++mi) {
#pragma unroll
        for (int jj = 0; jj < 2; ++jj) {
            int col = jbase + jj * 16 + mr;
            float bias = bl[col];
#pragma unroll
            for (int r = 0; r < 4; ++r) {
                int node = node0 + mi * 16 + quad * 4 + r;
                if (node >= n) continue;
                float v = acc[mi][jj][r] + bias;
                if (do_relu) v = fmaxf(v, 0.f);
                outb[(size_t)node * 128 + col] = f2bf(v);
            }
        }
    }
}

// ---------------- pool + head ----------------
__global__ __launch_bounds__(128) void k_pool(
    const unsigned short* __restrict__ hb, const int* __restrict__ batch,
    float* __restrict__ gsum, float* __restrict__ gcnt, int n)
{
    int f = threadIdx.x;  // 0..127
    int start = blockIdx.x * 256;
    if (start >= n) return;
    int end = min(start + 256, n);
    int cur = batch[start];
    float acc = 0.f, cnt = 0.f;
    for (int i = start; i < end; ++i) {
        int g = batch[i];
        if (g != cur) {
            atomicAdd(&gsum[cur * 128 + f], acc);
            if (f == 0) atomicAdd(&gcnt[cur], cnt);
            acc = 0.f; cnt = 0.f; cur = g;
        }
        acc += bf2f(hb[(size_t)i * 128 + f]);
        cnt += 1.f;
    }
    atomicAdd(&gsum[cur * 128 + f], acc);
    if (f == 0) atomicAdd(&gcnt[cur], cnt);
}

__global__ void k_final(const float* __restrict__ gsum, const float* __restrict__ gcnt,
                        const float* __restrict__ Wlin, const float* __restrict__ blin,
                        float* __restrict__ out)
{
    int g = blockIdx.x;   // 64
    int o = threadIdx.x;  // 64
    float inv = 1.f / fmaxf(gcnt[g], 1.f);
    float acc = 0.f;
    for (int k = 0; k < 128; ++k)
        acc += gsum[g * 128 + k] * Wlin[o * 128 + k];
    out[g * 64 + o] = acc * inv + blin[o];
}

extern "C" void kernel_launch(void* const* d_in, const int* in_sizes, int n_in,
                              void* d_out, int out_size, void* d_ws, size_t ws_size,
                              hipStream_t stream) {
    const float* x     = (const float*)d_in[0];
    const int*   ei    = (const int*)d_in[1];
    const int*   batch = (const int*)d_in[2];
    const float* W1l = (const float*)d_in[3];
    const float* b1l = (const float*)d_in[4];
    const float* W1r = (const float*)d_in[5];
    const float* W2l = (const float*)d_in[6];
    const float* b2l = (const float*)d_in[7];
    const float* W2r = (const float*)d_in[8];
    const float* W3l = (const float*)d_in[9];
    const float* b3l = (const float*)d_in[10];
    const float* W3r = (const float*)d_in[11];
    const float* Wlin = (const float*)d_in[12];
    const float* blin = (const float*)d_in[13];

    const int N = in_sizes[2];       // 50000
    const int E = in_sizes[1] / 2;   // 800000

    size_t off = 0;
    auto alloc = [&](size_t bytes) {
        void* p = (char*)d_ws + off;
        off += (bytes + 255) & ~(size_t)255;
        return p;
    };
    int* csr_start = (int*)alloc((size_t)(N + 1) * 4);
    int* cnt       = (int*)alloc((size_t)N * 4);
    int* pos       = (int*)alloc((size_t)N * 4);
    int* bsum      = (int*)alloc(256 * 4);
    int* boff      = (int*)alloc(256 * 4);
    int* csr_src   = (int*)alloc((size_t)E * 4);
    unsigned short* x_bf   = (unsigned short*)alloc((size_t)N * 128 * 2);
    unsigned short* hA     = (unsigned short*)alloc((size_t)N * 128 * 2);
    unsigned short* hB     = (unsigned short*)alloc((size_t)N * 128 * 2);
    unsigned short* agg_bf = (unsigned short*)alloc((size_t)N * 128 * 2);
    unsigned short* W1hi = (unsigned short*)alloc(128 * 256 * 2);
    unsigned short* W1lo = (unsigned short*)alloc(128 * 256 * 2);
    unsigned short* W2hi = (unsigned short*)alloc(128 * 256 * 2);
    unsigned short* W2lo = (unsigned short*)alloc(128 * 256 * 2);
    unsigned short* W3hi = (unsigned short*)alloc(128 * 256 * 2);
    unsigned short* W3lo = (unsigned short*)alloc(128 * 256 * 2);
    float* gsum = (float*)alloc((size_t)64 * 128 * 4);
    float* gcnt = (float*)alloc((size_t)64 * 4);
    (void)ws_size;

    hipMemsetAsync(cnt, 0, (size_t)N * 4, stream);
    hipMemsetAsync(gsum, 0, (size_t)64 * 128 * 4, stream);
    hipMemsetAsync(gcnt, 0, (size_t)64 * 4, stream);

    // CSR build (hierarchical scan)
    int nscan = (N + 255) / 256;  // 196
    k_hist<<<(E + 255) / 256, 256, 0, stream>>>(ei + E, cnt, E);
    k_scan1<<<nscan, 256, 0, stream>>>(cnt, bsum, N);
    k_scan2<<<1, 256, 0, stream>>>(bsum, boff, nscan, csr_start + N);
    k_scan3<<<nscan, 256, 0, stream>>>(cnt, boff, csr_start, pos, N);
    k_fill<<<(E + 255) / 256, 256, 0, stream>>>(ei, pos, csr_src, E);

    // Casts
    int n4 = N * 128 / 4;
    k_cast_x<<<(n4 + 255) / 256, 256, 0, stream>>>(x, x_bf, n4);
    k_cast_w<<<128, 256, 0, stream>>>(W1l, W1r, W1hi, W1lo);
    k_cast_w<<<128, 256, 0, stream>>>(W2l, W2r, W2hi, W2lo);
    k_cast_w<<<128, 256, 0, stream>>>(W3l, W3r, W3hi, W3lo);

    int agg_grid = (N + 3) / 4;
    int sage_grid = (N + 63) / 64;

    // Layer 1: x_bf -> hA (relu)
    k_agg<<<agg_grid, 256, 0, stream>>>(x_bf, csr_start, csr_src, agg_bf, N);
    k_sage<<<sage_grid, 256, 0, stream>>>(agg_bf, x_bf, W1hi, W1lo, b1l, hA, N, 1);
    // Layer 2: hA -> hB (relu)
    k_agg<<<agg_grid, 256, 0, stream>>>(hA, csr_start, csr_src, agg_bf, N);
    k_sage<<<sage_grid, 256, 0, stream>>>(agg_bf, hA, W2hi, W2lo, b2l, hB, N, 1);
    // Layer 3: hB -> hA (no relu)
    k_agg<<<agg_grid, 256, 0, stream>>>(hB, csr_start, csr_src, agg_bf, N);
    k_sage<<<sage_grid, 256, 0, stream>>>(agg_bf, hB, W3hi, W3lo, b3l, hA, N, 0);

    // Pool + head
    k_pool<<<(N + 255) / 256, 128, 0, stream>>>(hA, batch, gsum, gcnt, N);
    k_final<<<64, 64, 0, stream>>>(gsum, gcnt, Wlin, blin, (float*)d_out);
}

// Round 5
// 399.292 us; speedup vs baseline: 2.6549x; 1.0799x over previous
//
#include <hip/hip_runtime.h>

// HierarchicalGraphSAGE bf16-MFMA version, R5.
// N=50000, E=800000, D=128, OUT=64, G=64.
//
//  R5 change vs R4: k_pool (73us, 3.9% occupancy, 196x128 serial scalar loop)
//  rewritten wave-centric: one wave per 16-row strip, lane=feature-pair,
//  coalesced uint row loads, run-length flush on sorted batch. 3125 waves.
//  Everything else unchanged.

typedef __bf16 bf16x8 __attribute__((ext_vector_type(8)));
typedef float f32x4 __attribute__((ext_vector_type(4)));

static __device__ __forceinline__ float bf2f(unsigned short u) {
    union { unsigned u; float f; } c; c.u = (unsigned)u << 16; return c.f;
}
static __device__ __forceinline__ unsigned short f2bf(float f) {
    unsigned u = __builtin_bit_cast(unsigned, f);
    return (unsigned short)((u + 0x7fffu + ((u >> 16) & 1u)) >> 16);
}

// ---------------- CSR build ----------------
__global__ void k_hist(const int* __restrict__ dst, int* __restrict__ counts, int E) {
    int e = blockIdx.x * blockDim.x + threadIdx.x;
    if (e < E) atomicAdd(&counts[dst[e]], 1);
}

// Pass 1: per-block (256 counts) sum.
__global__ __launch_bounds__(256) void k_scan1(
    const int* __restrict__ counts, int* __restrict__ bsum, int n)
{
    __shared__ int s[4];
    int i = blockIdx.x * 256 + threadIdx.x;
    int v = (i < n) ? counts[i] : 0;
#pragma unroll
    for (int off = 1; off < 64; off <<= 1) v += __shfl_xor(v, off);
    if ((threadIdx.x & 63) == 0) s[threadIdx.x >> 6] = v;
    __syncthreads();
    if (threadIdx.x == 0) bsum[blockIdx.x] = s[0] + s[1] + s[2] + s[3];
}

// Pass 2: single block scans nb (<=256) block sums; exclusive offsets + total.
__global__ __launch_bounds__(256) void k_scan2(
    const int* __restrict__ bsum, int* __restrict__ boff, int nb, int* __restrict__ total_out)
{
    __shared__ int s[256];
    int t = threadIdx.x;
    int v = (t < nb) ? bsum[t] : 0;
    s[t] = v;
    __syncthreads();
#pragma unroll
    for (int off = 1; off < 256; off <<= 1) {
        int u = (t >= off) ? s[t - off] : 0;
        __syncthreads();
        s[t] += u;
        __syncthreads();
    }
    if (t < nb) boff[t] = s[t] - v;
    if (t == nb - 1) *total_out = s[t];
}

// Pass 3: local exclusive scan + block offset -> starts[i]; also pos[i]=starts[i].
__global__ __launch_bounds__(256) void k_scan3(
    const int* __restrict__ counts, const int* __restrict__ boff,
    int* __restrict__ starts, int* __restrict__ pos, int n)
{
    __shared__ int s[256];
    int t = threadIdx.x;
    int i = blockIdx.x * 256 + t;
    int v = (i < n) ? counts[i] : 0;
    s[t] = v;
    __syncthreads();
#pragma unroll
    for (int off = 1; off < 256; off <<= 1) {
        int u = (t >= off) ? s[t - off] : 0;
        __syncthreads();
        s[t] += u;
        __syncthreads();
    }
    if (i < n) {
        int st = boff[blockIdx.x] + s[t] - v;
        starts[i] = st;
        pos[i] = st;
    }
}

__global__ void k_fill(const int* __restrict__ ei, int* __restrict__ pos,
                       int* __restrict__ csr_src, int E) {
    int e = blockIdx.x * blockDim.x + threadIdx.x;
    if (e >= E) return;
    int s = ei[e];
    int d = ei[E + e];
    int p = atomicAdd(&pos[d], 1);
    csr_src[p] = s;
}

// ---------------- casts ----------------
__global__ void k_cast_x(const float* __restrict__ x, unsigned short* __restrict__ xb, int n4) {
    int i = blockIdx.x * blockDim.x + threadIdx.x;
    if (i >= n4) return;
    float4 v = *(const float4*)(x + (size_t)i * 4);
    ushort4 o;
    o.x = f2bf(v.x); o.y = f2bf(v.y); o.z = f2bf(v.z); o.w = f2bf(v.w);
    *(ushort4*)(xb + (size_t)i * 4) = o;
}

// Wcat = [Wl | Wr] rows [128 x 256], split into bf16 hi + lo.
__global__ void k_cast_w(const float* __restrict__ Wl, const float* __restrict__ Wr,
                         unsigned short* __restrict__ Whi, unsigned short* __restrict__ Wlo) {
    int row = blockIdx.x;    // 128
    int col = threadIdx.x;   // 256
    float w = (col < 128) ? Wl[row * 128 + col] : Wr[row * 128 + col - 128];
    unsigned short hi = f2bf(w);
    float lo = w - bf2f(hi);
    Whi[row * 256 + col] = hi;
    Wlo[row * 256 + col] = f2bf(lo);
}

// ---------------- aggregate: wave/node, batched indices, 4-deep loads ------
__global__ __launch_bounds__(256) void k_agg(
    const unsigned short* __restrict__ hb, const int* __restrict__ starts,
    const int* __restrict__ csr, unsigned short* __restrict__ aggb, int n)
{
    int node = blockIdx.x * 4 + (threadIdx.x >> 6);
    int lane = threadIdx.x & 63;
    if (node >= n) return;
    int s = starts[node], e = starts[node + 1];
    const unsigned short* hlane = hb + lane * 2;
    float ax = 0.f, ay = 0.f;
    for (int base = s; base < e; base += 64) {
        int cnt = min(64, e - base);
        int idx = (base + lane < e) ? csr[base + lane] : 0;
        int j = 0;
        for (; j + 4 <= cnt; j += 4) {
            int s0 = __shfl(idx, j + 0);
            int s1 = __shfl(idx, j + 1);
            int s2 = __shfl(idx, j + 2);
            int s3 = __shfl(idx, j + 3);
            unsigned v0 = *(const unsigned*)(hlane + (size_t)s0 * 128);
            unsigned v1 = *(const unsigned*)(hlane + (size_t)s1 * 128);
            unsigned v2 = *(const unsigned*)(hlane + (size_t)s2 * 128);
            unsigned v3 = *(const unsigned*)(hlane + (size_t)s3 * 128);
            ax += __builtin_bit_cast(float, v0 << 16);
            ay += __builtin_bit_cast(float, v0 & 0xffff0000u);
            ax += __builtin_bit_cast(float, v1 << 16);
            ay += __builtin_bit_cast(float, v1 & 0xffff0000u);
            ax += __builtin_bit_cast(float, v2 << 16);
            ay += __builtin_bit_cast(float, v2 & 0xffff0000u);
            ax += __builtin_bit_cast(float, v3 << 16);
            ay += __builtin_bit_cast(float, v3 & 0xffff0000u);
        }
        for (; j < cnt; ++j) {
            int s0 = __shfl(idx, j);
            unsigned v0 = *(const unsigned*)(hlane + (size_t)s0 * 128);
            ax += __builtin_bit_cast(float, v0 << 16);
            ay += __builtin_bit_cast(float, v0 & 0xffff0000u);
        }
    }
    unsigned o = (unsigned)f2bf(ax) | ((unsigned)f2bf(ay) << 16);
    *(unsigned*)(aggb + (size_t)node * 128 + lane * 2) = o;
}

// ---------------- SAGE layer GEMM via bf16 MFMA ----------------
// C[m][j] = relu?( bl[j] + sum_k A[m][k]*W[j][k] ), A=[agg|h] (K=256).
// Block 256 thr = 4 waves, tile 64 m x 128 j. Wave w owns j-strip
// [32w, 32w+32): B frags (hi/lo x 2 jj) stay in VGPRs across 4 m-subtiles.
__global__ __launch_bounds__(256) void k_sage(
    const unsigned short* __restrict__ aggb, const unsigned short* __restrict__ hb,
    const unsigned short* __restrict__ Whi, const unsigned short* __restrict__ Wlo,
    const float* __restrict__ bl, unsigned short* __restrict__ outb, int n, int do_relu)
{
    __shared__ unsigned short sA[64 * 264];  // 33792 B
    int node0 = blockIdx.x * 64;
    int t = threadIdx.x;

    for (int q = t; q < 2048; q += 256) {
        int nd = q >> 5;
        int c = q & 31;
        int node = node0 + nd;
        uint4 v = make_uint4(0u, 0u, 0u, 0u);
        if (node < n) {
            const unsigned short* src = (c < 16)
                ? (aggb + (size_t)node * 128 + c * 8)
                : (hb + (size_t)node * 128 + (c - 16) * 8);
            v = *(const uint4*)src;
        }
        *(uint4*)(sA + nd * 264 + c * 8) = v;
    }
    __syncthreads();

    int wv = t >> 6;
    int l = t & 63;
    int quad = l >> 4;
    int mr = l & 15;
    int jbase = wv * 32;

    f32x4 acc[4][2];
#pragma unroll
    for (int mi = 0; mi < 4; ++mi)
#pragma unroll
        for (int jj = 0; jj < 2; ++jj) acc[mi][jj] = (f32x4){0.f, 0.f, 0.f, 0.f};

    for (int s = 0; s < 8; ++s) {
        int koff = s * 32 + quad * 8;
        bf16x8 bh[2], bo[2];
#pragma unroll
        for (int jj = 0; jj < 2; ++jj) {
            size_t wo = (size_t)(jbase + jj * 16 + mr) * 256 + koff;
            bh[jj] = __builtin_bit_cast(bf16x8, *(const uint4*)(Whi + wo));
            bo[jj] = __builtin_bit_cast(bf16x8, *(const uint4*)(Wlo + wo));
        }
#pragma unroll
        for (int mi = 0; mi < 4; ++mi) {
            bf16x8 a = __builtin_bit_cast(
                bf16x8, *(const uint4*)(sA + (mi * 16 + mr) * 264 + koff));
#pragma unroll
            for (int jj = 0; jj < 2; ++jj) {
                acc[mi][jj] = __builtin_amdgcn_mfma_f32_16x16x32_bf16(a, bh[jj], acc[mi][jj], 0, 0, 0);
                acc[mi][jj] = __builtin_amdgcn_mfma_f32_16x16x32_bf16(a, bo[jj], acc[mi][jj], 0, 0, 0);
            }
        }
    }

#pragma unroll
    for (int mi = 0; mi < 4; ++mi) {
#pragma unroll
        for (int jj = 0; jj < 2; ++jj) {
            int col = jbase + jj * 16 + mr;
            float bias = bl[col];
#pragma unroll
            for (int r = 0; r < 4; ++r) {
                int node = node0 + mi * 16 + quad * 4 + r;
                if (node >= n) continue;
                float v = acc[mi][jj][r] + bias;
                if (do_relu) v = fmaxf(v, 0.f);
                outb[(size_t)node * 128 + col] = f2bf(v);
            }
        }
    }
}

// ---------------- pool: one wave per 16-row strip, run-length flush --------
#define POOL_ROWS 16
__global__ __launch_bounds__(256) void k_pool(
    const unsigned short* __restrict__ hb, const int* __restrict__ batch,
    float* __restrict__ gsum, float* __restrict__ gcnt, int n)
{
    int wave = (blockIdx.x * 256 + threadIdx.x) >> 6;
    int lane = threadIdx.x & 63;
    int r0 = wave * POOL_ROWS;
    if (r0 >= n) return;
    int r1 = min(r0 + POOL_ROWS, n);
    int cur = batch[r0];
    float ax = 0.f, ay = 0.f, cnt = 0.f;
    for (int i = r0; i < r1; ++i) {
        int g = batch[i];
        unsigned v = *(const unsigned*)(hb + (size_t)i * 128 + lane * 2);
        if (g != cur) {
            atomicAdd(&gsum[cur * 128 + lane * 2], ax);
            atomicAdd(&gsum[cur * 128 + lane * 2 + 1], ay);
            if (lane == 0) atomicAdd(&gcnt[cur], cnt);
            ax = 0.f; ay = 0.f; cnt = 0.f; cur = g;
        }
        ax += __builtin_bit_cast(float, v << 16);
        ay += __builtin_bit_cast(float, v & 0xffff0000u);
        cnt += 1.f;
    }
    atomicAdd(&gsum[cur * 128 + lane * 2], ax);
    atomicAdd(&gsum[cur * 128 + lane * 2 + 1], ay);
    if (lane == 0) atomicAdd(&gcnt[cur], cnt);
}

__global__ void k_final(const float* __restrict__ gsum, const float* __restrict__ gcnt,
                        const float* __restrict__ Wlin, const float* __restrict__ blin,
                        float* __restrict__ out)
{
    int g = blockIdx.x;   // 64
    int o = threadIdx.x;  // 64
    float inv = 1.f / fmaxf(gcnt[g], 1.f);
    float acc = 0.f;
    for (int k = 0; k < 128; ++k)
        acc += gsum[g * 128 + k] * Wlin[o * 128 + k];
    out[g * 64 + o] = acc * inv + blin[o];
}

extern "C" void kernel_launch(void* const* d_in, const int* in_sizes, int n_in,
                              void* d_out, int out_size, void* d_ws, size_t ws_size,
                              hipStream_t stream) {
    const float* x     = (const float*)d_in[0];
    const int*   ei    = (const int*)d_in[1];
    const int*   batch = (const int*)d_in[2];
    const float* W1l = (const float*)d_in[3];
    const float* b1l = (const float*)d_in[4];
    const float* W1r = (const float*)d_in[5];
    const float* W2l = (const float*)d_in[6];
    const float* b2l = (const float*)d_in[7];
    const float* W2r = (const float*)d_in[8];
    const float* W3l = (const float*)d_in[9];
    const float* b3l = (const float*)d_in[10];
    const float* W3r = (const float*)d_in[11];
    const float* Wlin = (const float*)d_in[12];
    const float* blin = (const float*)d_in[13];

    const int N = in_sizes[2];       // 50000
    const int E = in_sizes[1] / 2;   // 800000

    size_t off = 0;
    auto alloc = [&](size_t bytes) {
        void* p = (char*)d_ws + off;
        off += (bytes + 255) & ~(size_t)255;
        return p;
    };
    int* csr_start = (int*)alloc((size_t)(N + 1) * 4);
    int* cnt       = (int*)alloc((size_t)N * 4);
    int* pos       = (int*)alloc((size_t)N * 4);
    int* bsum      = (int*)alloc(256 * 4);
    int* boff      = (int*)alloc(256 * 4);
    int* csr_src   = (int*)alloc((size_t)E * 4);
    unsigned short* x_bf   = (unsigned short*)alloc((size_t)N * 128 * 2);
    unsigned short* hA     = (unsigned short*)alloc((size_t)N * 128 * 2);
    unsigned short* hB     = (unsigned short*)alloc((size_t)N * 128 * 2);
    unsigned short* agg_bf = (unsigned short*)alloc((size_t)N * 128 * 2);
    unsigned short* W1hi = (unsigned short*)alloc(128 * 256 * 2);
    unsigned short* W1lo = (unsigned short*)alloc(128 * 256 * 2);
    unsigned short* W2hi = (unsigned short*)alloc(128 * 256 * 2);
    unsigned short* W2lo = (unsigned short*)alloc(128 * 256 * 2);
    unsigned short* W3hi = (unsigned short*)alloc(128 * 256 * 2);
    unsigned short* W3lo = (unsigned short*)alloc(128 * 256 * 2);
    float* gsum = (float*)alloc((size_t)64 * 128 * 4);
    float* gcnt = (float*)alloc((size_t)64 * 4);
    (void)ws_size;

    hipMemsetAsync(cnt, 0, (size_t)N * 4, stream);
    hipMemsetAsync(gsum, 0, (size_t)64 * 128 * 4, stream);
    hipMemsetAsync(gcnt, 0, (size_t)64 * 4, stream);

    // CSR build (hierarchical scan)
    int nscan = (N + 255) / 256;  // 196
    k_hist<<<(E + 255) / 256, 256, 0, stream>>>(ei + E, cnt, E);
    k_scan1<<<nscan, 256, 0, stream>>>(cnt, bsum, N);
    k_scan2<<<1, 256, 0, stream>>>(bsum, boff, nscan, csr_start + N);
    k_scan3<<<nscan, 256, 0, stream>>>(cnt, boff, csr_start, pos, N);
    k_fill<<<(E + 255) / 256, 256, 0, stream>>>(ei, pos, csr_src, E);

    // Casts
    int n4 = N * 128 / 4;
    k_cast_x<<<(n4 + 255) / 256, 256, 0, stream>>>(x, x_bf, n4);
    k_cast_w<<<128, 256, 0, stream>>>(W1l, W1r, W1hi, W1lo);
    k_cast_w<<<128, 256, 0, stream>>>(W2l, W2r, W2hi, W2lo);
    k_cast_w<<<128, 256, 0, stream>>>(W3l, W3r, W3hi, W3lo);

    int agg_grid = (N + 3) / 4;
    int sage_grid = (N + 63) / 64;

    // Layer 1: x_bf -> hA (relu)
    k_agg<<<agg_grid, 256, 0, stream>>>(x_bf, csr_start, csr_src, agg_bf, N);
    k_sage<<<sage_grid, 256, 0, stream>>>(agg_bf, x_bf, W1hi, W1lo, b1l, hA, N, 1);
    // Layer 2: hA -> hB (relu)
    k_agg<<<agg_grid, 256, 0, stream>>>(hA, csr_start, csr_src, agg_bf, N);
    k_sage<<<sage_grid, 256, 0, stream>>>(agg_bf, hA, W2hi, W2lo, b2l, hB, N, 1);
    // Layer 3: hB -> hA (no relu)
    k_agg<<<agg_grid, 256, 0, stream>>>(hB, csr_start, csr_src, agg_bf, N);
    k_sage<<<sage_grid, 256, 0, stream>>>(agg_bf, hB, W3hi, W3lo, b3l, hA, N, 0);

    // Pool + head
    int pool_waves = (N + POOL_ROWS - 1) / POOL_ROWS;
    int pool_blocks = (pool_waves + 3) / 4;
    k_pool<<<pool_blocks, 256, 0, stream>>>(hA, batch, gsum, gcnt, N);
    k_final<<<64, 64, 0, stream>>>(gsum, gcnt, Wlin, blin, (float*)d_out);
}

// Round 6
// 339.252 us; speedup vs baseline: 3.1248x; 1.1770x over previous
//
#include <hip/hip_runtime.h>

// HierarchicalGraphSAGE bf16-MFMA version, R6.
// N=50000, E=800000, D=128, OUT=64, G=64.
//
//  R6 change vs R5: k_hist + k_fill (random device atomics + 52MB write
//  amplification from cross-XCD scattered 4B stores) replaced by a
//  bucket-confined counting sort:
//    k_bincount  : per-(block,bucket) histogram, LDS atomics only
//    scan matrix : 391x160 exclusive scan (hierarchical)
//    k_binscatter: edges -> binned[] grouped by 128-node bucket, private
//                  (block,bucket) segments, no global atomics
//    k_hist2     : per-node counts from contiguous binned range, LDS atomics
//    scan nodes  : csr_start
//    k_fillfine  : per-bucket fine scatter, LDS slot counters, csr writes
//                  confined to ~8KB per block (single-XCD lines).
//  binned aliases agg_bf (dead until layer 1).

typedef __bf16 bf16x8 __attribute__((ext_vector_type(8)));
typedef float f32x4 __attribute__((ext_vector_type(4)));

#define BINB 160          // binning blocks
#define NBMAX 512         // max buckets (N <= 65536)

static __device__ __forceinline__ float bf2f(unsigned short u) {
    union { unsigned u; float f; } c; c.u = (unsigned)u << 16; return c.f;
}
static __device__ __forceinline__ unsigned short f2bf(float f) {
    unsigned u = __builtin_bit_cast(unsigned, f);
    return (unsigned short)((u + 0x7fffu + ((u >> 16) & 1u)) >> 16);
}

// ---------------- bucket counting sort ----------------
__global__ __launch_bounds__(256) void k_bincount(
    const int* __restrict__ dst, int* __restrict__ cnt_mat, int E, int nb, int epb)
{
    __shared__ int lc[NBMAX];
    for (int i = threadIdx.x; i < nb; i += 256) lc[i] = 0;
    __syncthreads();
    int b0 = blockIdx.x * epb;
    int b1 = min(b0 + epb, E);
    for (int i = b0 + threadIdx.x; i < b1; i += 256)
        atomicAdd(&lc[dst[i] >> 7], 1);
    __syncthreads();
    for (int i = threadIdx.x; i < nb; i += 256)
        cnt_mat[i * BINB + blockIdx.x] = lc[i];
}

__global__ __launch_bounds__(256) void k_binscatter(
    const int* __restrict__ ei, const int* __restrict__ off_mat,
    uint2* __restrict__ binned, int E, int nb, int epb)
{
    __shared__ int lofs[NBMAX];
    __shared__ int lcnt[NBMAX];
    for (int i = threadIdx.x; i < nb; i += 256) {
        lofs[i] = off_mat[i * BINB + blockIdx.x];
        lcnt[i] = 0;
    }
    __syncthreads();
    int b0 = blockIdx.x * epb;
    int b1 = min(b0 + epb, E);
    for (int i = b0 + threadIdx.x; i < b1; i += 256) {
        int s = ei[i];
        int d = ei[E + i];
        int b = d >> 7;
        int r = atomicAdd(&lcnt[b], 1);
        binned[lofs[b] + r] = make_uint2((unsigned)s, (unsigned)d);
    }
}

// Per-node counts from the bucket's contiguous binned range (LDS atomics).
__global__ __launch_bounds__(256) void k_hist2(
    const uint2* __restrict__ binned, const int* __restrict__ off_mat,
    int* __restrict__ counts, int E, int nb, int n)
{
    __shared__ int lc[128];
    int b = blockIdx.x;
    if (threadIdx.x < 128) lc[threadIdx.x] = 0;
    __syncthreads();
    int bs = off_mat[b * BINB];
    int be = (b == nb - 1) ? E : off_mat[(b + 1) * BINB];
    for (int i = bs + threadIdx.x; i < be; i += 256)
        atomicAdd(&lc[binned[i].y & 127], 1);
    __syncthreads();
    int node = (b << 7) + threadIdx.x;
    if (threadIdx.x < 128 && node < n) counts[node] = lc[threadIdx.x];
}

// Fine scatter: slot counters in LDS, csr writes confined to bucket range.
__global__ __launch_bounds__(256) void k_fillfine(
    const uint2* __restrict__ binned, const int* __restrict__ off_mat,
    const int* __restrict__ starts, int* __restrict__ csr_src, int E, int nb, int n)
{
    __shared__ int lpos[128];
    int b = blockIdx.x;
    int node0 = b << 7;
    if (threadIdx.x < 128) {
        int node = node0 + threadIdx.x;
        lpos[threadIdx.x] = (node < n) ? starts[node] : 0;
    }
    __syncthreads();
    int bs = off_mat[b * BINB];
    int be = (b == nb - 1) ? E : off_mat[(b + 1) * BINB];
    for (int i = bs + threadIdx.x; i < be; i += 256) {
        uint2 e = binned[i];
        int slot = atomicAdd(&lpos[e.y & 127], 1);
        csr_src[slot] = (int)e.x;
    }
}

// ---------------- hierarchical scan ----------------
__global__ __launch_bounds__(256) void k_scan1(
    const int* __restrict__ counts, int* __restrict__ bsum, int n)
{
    __shared__ int s[4];
    int i = blockIdx.x * 256 + threadIdx.x;
    int v = (i < n) ? counts[i] : 0;
#pragma unroll
    for (int off = 1; off < 64; off <<= 1) v += __shfl_xor(v, off);
    if ((threadIdx.x & 63) == 0) s[threadIdx.x >> 6] = v;
    __syncthreads();
    if (threadIdx.x == 0) bsum[blockIdx.x] = s[0] + s[1] + s[2] + s[3];
}

__global__ __launch_bounds__(256) void k_scan2(
    const int* __restrict__ bsum, int* __restrict__ boff, int nb, int* __restrict__ total_out)
{
    __shared__ int s[256];
    int t = threadIdx.x;
    int v = (t < nb) ? bsum[t] : 0;
    s[t] = v;
    __syncthreads();
#pragma unroll
    for (int off = 1; off < 256; off <<= 1) {
        int u = (t >= off) ? s[t - off] : 0;
        __syncthreads();
        s[t] += u;
        __syncthreads();
    }
    if (t < nb) boff[t] = s[t] - v;
    if (t == nb - 1) *total_out = s[t];
}

__global__ __launch_bounds__(256) void k_scan3m(
    const int* __restrict__ counts, const int* __restrict__ boff,
    int* __restrict__ starts, int n)
{
    __shared__ int s[256];
    int t = threadIdx.x;
    int i = blockIdx.x * 256 + t;
    int v = (i < n) ? counts[i] : 0;
    s[t] = v;
    __syncthreads();
#pragma unroll
    for (int off = 1; off < 256; off <<= 1) {
        int u = (t >= off) ? s[t - off] : 0;
        __syncthreads();
        s[t] += u;
        __syncthreads();
    }
    if (i < n) starts[i] = boff[blockIdx.x] + s[t] - v;
}

// ---------------- casts ----------------
__global__ void k_cast_x(const float* __restrict__ x, unsigned short* __restrict__ xb, int n4) {
    int i = blockIdx.x * blockDim.x + threadIdx.x;
    if (i >= n4) return;
    float4 v = *(const float4*)(x + (size_t)i * 4);
    ushort4 o;
    o.x = f2bf(v.x); o.y = f2bf(v.y); o.z = f2bf(v.z); o.w = f2bf(v.w);
    *(ushort4*)(xb + (size_t)i * 4) = o;
}

// Wcat = [Wl | Wr] rows [128 x 256], split into bf16 hi + lo.
__global__ void k_cast_w(const float* __restrict__ Wl, const float* __restrict__ Wr,
                         unsigned short* __restrict__ Whi, unsigned short* __restrict__ Wlo) {
    int row = blockIdx.x;    // 128
    int col = threadIdx.x;   // 256
    float w = (col < 128) ? Wl[row * 128 + col] : Wr[row * 128 + col - 128];
    unsigned short hi = f2bf(w);
    float lo = w - bf2f(hi);
    Whi[row * 256 + col] = hi;
    Wlo[row * 256 + col] = f2bf(lo);
}

// ---------------- aggregate: wave/node, batched indices, 4-deep loads ------
__global__ __launch_bounds__(256) void k_agg(
    const unsigned short* __restrict__ hb, const int* __restrict__ starts,
    const int* __restrict__ csr, unsigned short* __restrict__ aggb, int n)
{
    int node = blockIdx.x * 4 + (threadIdx.x >> 6);
    int lane = threadIdx.x & 63;
    if (node >= n) return;
    int s = starts[node], e = starts[node + 1];
    const unsigned short* hlane = hb + lane * 2;
    float ax = 0.f, ay = 0.f;
    for (int base = s; base < e; base += 64) {
        int cnt = min(64, e - base);
        int idx = (base + lane < e) ? csr[base + lane] : 0;
        int j = 0;
        for (; j + 4 <= cnt; j += 4) {
            int s0 = __shfl(idx, j + 0);
            int s1 = __shfl(idx, j + 1);
            int s2 = __shfl(idx, j + 2);
            int s3 = __shfl(idx, j + 3);
            unsigned v0 = *(const unsigned*)(hlane + (size_t)s0 * 128);
            unsigned v1 = *(const unsigned*)(hlane + (size_t)s1 * 128);
            unsigned v2 = *(const unsigned*)(hlane + (size_t)s2 * 128);
            unsigned v3 = *(const unsigned*)(hlane + (size_t)s3 * 128);
            ax += __builtin_bit_cast(float, v0 << 16);
            ay += __builtin_bit_cast(float, v0 & 0xffff0000u);
            ax += __builtin_bit_cast(float, v1 << 16);
            ay += __builtin_bit_cast(float, v1 & 0xffff0000u);
            ax += __builtin_bit_cast(float, v2 << 16);
            ay += __builtin_bit_cast(float, v2 & 0xffff0000u);
            ax += __builtin_bit_cast(float, v3 << 16);
            ay += __builtin_bit_cast(float, v3 & 0xffff0000u);
        }
        for (; j < cnt; ++j) {
            int s0 = __shfl(idx, j);
            unsigned v0 = *(const unsigned*)(hlane + (size_t)s0 * 128);
            ax += __builtin_bit_cast(float, v0 << 16);
            ay += __builtin_bit_cast(float, v0 & 0xffff0000u);
        }
    }
    unsigned o = (unsigned)f2bf(ax) | ((unsigned)f2bf(ay) << 16);
    *(unsigned*)(aggb + (size_t)node * 128 + lane * 2) = o;
}

// ---------------- SAGE layer GEMM via bf16 MFMA ----------------
__global__ __launch_bounds__(256) void k_sage(
    const unsigned short* __restrict__ aggb, const unsigned short* __restrict__ hb,
    const unsigned short* __restrict__ Whi, const unsigned short* __restrict__ Wlo,
    const float* __restrict__ bl, unsigned short* __restrict__ outb, int n, int do_relu)
{
    __shared__ unsigned short sA[64 * 264];  // 33792 B
    int node0 = blockIdx.x * 64;
    int t = threadIdx.x;

    for (int q = t; q < 2048; q += 256) {
        int nd = q >> 5;
        int c = q & 31;
        int node = node0 + nd;
        uint4 v = make_uint4(0u, 0u, 0u, 0u);
        if (node < n) {
            const unsigned short* src = (c < 16)
                ? (aggb + (size_t)node * 128 + c * 8)
                : (hb + (size_t)node * 128 + (c - 16) * 8);
            v = *(const uint4*)src;
        }
        *(uint4*)(sA + nd * 264 + c * 8) = v;
    }
    __syncthreads();

    int wv = t >> 6;
    int l = t & 63;
    int quad = l >> 4;
    int mr = l & 15;
    int jbase = wv * 32;

    f32x4 acc[4][2];
#pragma unroll
    for (int mi = 0; mi < 4; ++mi)
#pragma unroll
        for (int jj = 0; jj < 2; ++jj) acc[mi][jj] = (f32x4){0.f, 0.f, 0.f, 0.f};

    for (int s = 0; s < 8; ++s) {
        int koff = s * 32 + quad * 8;
        bf16x8 bh[2], bo[2];
#pragma unroll
        for (int jj = 0; jj < 2; ++jj) {
            size_t wo = (size_t)(jbase + jj * 16 + mr) * 256 + koff;
            bh[jj] = __builtin_bit_cast(bf16x8, *(const uint4*)(Whi + wo));
            bo[jj] = __builtin_bit_cast(bf16x8, *(const uint4*)(Wlo + wo));
        }
#pragma unroll
        for (int mi = 0; mi < 4; ++mi) {
            bf16x8 a = __builtin_bit_cast(
                bf16x8, *(const uint4*)(sA + (mi * 16 + mr) * 264 + koff));
#pragma unroll
            for (int jj = 0; jj < 2; ++jj) {
                acc[mi][jj] = __builtin_amdgcn_mfma_f32_16x16x32_bf16(a, bh[jj], acc[mi][jj], 0, 0, 0);
                acc[mi][jj] = __builtin_amdgcn_mfma_f32_16x16x32_bf16(a, bo[jj], acc[mi][jj], 0, 0, 0);
            }
        }
    }

#pragma unroll
    for (int mi = 0; mi < 4; ++mi) {
#pragma unroll
        for (int jj = 0; jj < 2; ++jj) {
            int col = jbase + jj * 16 + mr;
            float bias = bl[col];
#pragma unroll
            for (int r = 0; r < 4; ++r) {
                int node = node0 + mi * 16 + quad * 4 + r;
                if (node >= n) continue;
                float v = acc[mi][jj][r] + bias;
                if (do_relu) v = fmaxf(v, 0.f);
                outb[(size_t)node * 128 + col] = f2bf(v);
            }
        }
    }
}

// ---------------- pool: one wave per 16-row strip, run-length flush --------
#define POOL_ROWS 16
__global__ __launch_bounds__(256) void k_pool(
    const unsigned short* __restrict__ hb, const int* __restrict__ batch,
    float* __restrict__ gsum, float* __restrict__ gcnt, int n)
{
    int wave = (blockIdx.x * 256 + threadIdx.x) >> 6;
    int lane = threadIdx.x & 63;
    int r0 = wave * POOL_ROWS;
    if (r0 >= n) return;
    int r1 = min(r0 + POOL_ROWS, n);
    int cur = batch[r0];
    float ax = 0.f, ay = 0.f, cnt = 0.f;
    for (int i = r0; i < r1; ++i) {
        int g = batch[i];
        unsigned v = *(const unsigned*)(hb + (size_t)i * 128 + lane * 2);
        if (g != cur) {
            atomicAdd(&gsum[cur * 128 + lane * 2], ax);
            atomicAdd(&gsum[cur * 128 + lane * 2 + 1], ay);
            if (lane == 0) atomicAdd(&gcnt[cur], cnt);
            ax = 0.f; ay = 0.f; cnt = 0.f; cur = g;
        }
        ax += __builtin_bit_cast(float, v << 16);
        ay += __builtin_bit_cast(float, v & 0xffff0000u);
        cnt += 1.f;
    }
    atomicAdd(&gsum[cur * 128 + lane * 2], ax);
    atomicAdd(&gsum[cur * 128 + lane * 2 + 1], ay);
    if (lane == 0) atomicAdd(&gcnt[cur], cnt);
}

__global__ void k_final(const float* __restrict__ gsum, const float* __restrict__ gcnt,
                        const float* __restrict__ Wlin, const float* __restrict__ blin,
                        float* __restrict__ out)
{
    int g = blockIdx.x;   // 64
    int o = threadIdx.x;  // 64
    float inv = 1.f / fmaxf(gcnt[g], 1.f);
    float acc = 0.f;
    for (int k = 0; k < 128; ++k)
        acc += gsum[g * 128 + k] * Wlin[o * 128 + k];
    out[g * 64 + o] = acc * inv + blin[o];
}

extern "C" void kernel_launch(void* const* d_in, const int* in_sizes, int n_in,
                              void* d_out, int out_size, void* d_ws, size_t ws_size,
                              hipStream_t stream) {
    const float* x     = (const float*)d_in[0];
    const int*   ei    = (const int*)d_in[1];
    const int*   batch = (const int*)d_in[2];
    const float* W1l = (const float*)d_in[3];
    const float* b1l = (const float*)d_in[4];
    const float* W1r = (const float*)d_in[5];
    const float* W2l = (const float*)d_in[6];
    const float* b2l = (const float*)d_in[7];
    const float* W2r = (const float*)d_in[8];
    const float* W3l = (const float*)d_in[9];
    const float* b3l = (const float*)d_in[10];
    const float* W3r = (const float*)d_in[11];
    const float* Wlin = (const float*)d_in[12];
    const float* blin = (const float*)d_in[13];

    const int N = in_sizes[2];       // 50000
    const int E = in_sizes[1] / 2;   // 800000
    const int nb = (N + 127) >> 7;   // 391 buckets
    const int epb = (E + BINB - 1) / BINB;  // 5000 edges per bin block

    size_t off = 0;
    auto alloc = [&](size_t bytes) {
        void* p = (char*)d_ws + off;
        off += (bytes + 255) & ~(size_t)255;
        return p;
    };
    int* csr_start = (int*)alloc((size_t)(N + 1) * 4);
    int* cnt       = (int*)alloc((size_t)N * 4);
    int* cnt_mat   = (int*)alloc((size_t)nb * BINB * 4);
    int* off_mat   = (int*)alloc((size_t)nb * BINB * 4);
    int* bsum      = (int*)alloc(256 * 4);
    int* boff      = (int*)alloc(256 * 4);
    int* bsum2     = (int*)alloc(256 * 4);
    int* boff2     = (int*)alloc(256 * 4);
    int* tot_scratch = (int*)alloc(256);
    int* csr_src   = (int*)alloc((size_t)E * 4);
    unsigned short* x_bf   = (unsigned short*)alloc((size_t)N * 128 * 2);
    unsigned short* hA     = (unsigned short*)alloc((size_t)N * 128 * 2);
    unsigned short* hB     = (unsigned short*)alloc((size_t)N * 128 * 2);
    unsigned short* agg_bf = (unsigned short*)alloc((size_t)N * 128 * 2);
    unsigned short* W1hi = (unsigned short*)alloc(128 * 256 * 2);
    unsigned short* W1lo = (unsigned short*)alloc(128 * 256 * 2);
    unsigned short* W2hi = (unsigned short*)alloc(128 * 256 * 2);
    unsigned short* W2lo = (unsigned short*)alloc(128 * 256 * 2);
    unsigned short* W3hi = (unsigned short*)alloc(128 * 256 * 2);
    unsigned short* W3lo = (unsigned short*)alloc(128 * 256 * 2);
    float* gsum = (float*)alloc((size_t)64 * 128 * 4);
    float* gcnt = (float*)alloc((size_t)64 * 4);
    (void)ws_size;

    // binned aliases agg_bf: dead until first k_agg, E*8 <= N*256 bytes.
    uint2* binned = (uint2*)agg_bf;

    hipMemsetAsync(gsum, 0, (size_t)64 * 128 * 4, stream);
    hipMemsetAsync(gcnt, 0, (size_t)64 * 4, stream);

    // --- CSR build via bucket counting sort ---
    int nmat = nb * BINB;                  // 62560
    int nscan_m = (nmat + 255) / 256;      // 245
    int nscan_n = (N + 255) / 256;         // 196

    k_bincount<<<BINB, 256, 0, stream>>>(ei + E, cnt_mat, E, nb, epb);
    k_scan1<<<nscan_m, 256, 0, stream>>>(cnt_mat, bsum2, nmat);
    k_scan2<<<1, 256, 0, stream>>>(bsum2, boff2, nscan_m, tot_scratch);
    k_scan3m<<<nscan_m, 256, 0, stream>>>(cnt_mat, boff2, off_mat, nmat);
    k_binscatter<<<BINB, 256, 0, stream>>>(ei, off_mat, binned, E, nb, epb);
    k_hist2<<<nb, 256, 0, stream>>>(binned, off_mat, cnt, E, nb, N);
    k_scan1<<<nscan_n, 256, 0, stream>>>(cnt, bsum, N);
    k_scan2<<<1, 256, 0, stream>>>(bsum, boff, nscan_n, csr_start + N);
    k_scan3m<<<nscan_n, 256, 0, stream>>>(cnt, boff, csr_start, N);
    k_fillfine<<<nb, 256, 0, stream>>>(binned, off_mat, csr_start, csr_src, E, nb, N);

    // Casts
    int n4 = N * 128 / 4;
    k_cast_x<<<(n4 + 255) / 256, 256, 0, stream>>>(x, x_bf, n4);
    k_cast_w<<<128, 256, 0, stream>>>(W1l, W1r, W1hi, W1lo);
    k_cast_w<<<128, 256, 0, stream>>>(W2l, W2r, W2hi, W2lo);
    k_cast_w<<<128, 256, 0, stream>>>(W3l, W3r, W3hi, W3lo);

    int agg_grid = (N + 3) / 4;
    int sage_grid = (N + 63) / 64;

    // Layer 1: x_bf -> hA (relu)
    k_agg<<<agg_grid, 256, 0, stream>>>(x_bf, csr_start, csr_src, agg_bf, N);
    k_sage<<<sage_grid, 256, 0, stream>>>(agg_bf, x_bf, W1hi, W1lo, b1l, hA, N, 1);
    // Layer 2: hA -> hB (relu)
    k_agg<<<agg_grid, 256, 0, stream>>>(hA, csr_start, csr_src, agg_bf, N);
    k_sage<<<sage_grid, 256, 0, stream>>>(agg_bf, hA, W2hi, W2lo, b2l, hB, N, 1);
    // Layer 3: hB -> hA (no relu)
    k_agg<<<agg_grid, 256, 0, stream>>>(hB, csr_start, csr_src, agg_bf, N);
    k_sage<<<sage_grid, 256, 0, stream>>>(agg_bf, hB, W3hi, W3lo, b3l, hA, N, 0);

    // Pool + head
    int pool_waves = (N + POOL_ROWS - 1) / POOL_ROWS;
    int pool_blocks = (pool_waves + 3) / 4;
    k_pool<<<pool_blocks, 256, 0, stream>>>(hA, batch, gsum, gcnt, N);
    k_final<<<64, 64, 0, stream>>>(gsum, gcnt, Wlin, blin, (float*)d_out);
}